// Round 6
// baseline (3016.140 us; speedup 1.0000x reference)
//
#include <hip/hip_runtime.h>

// SolvGNNV6 round 6: fused gather+GEMM conv layer (eliminates the hB
// intermediate round-trip). Gather 128-row aggregated A-tile into swizzled
// LDS, then BM=128 x BN=256 MFMA GEMM, K=256, B staged via global_load_lds.

#define NN 81920     // nodes
#define NE 327680    // edges
#define NB 2048      // graphs
#define H 256
#define INDIM 74
#define KPAD 128     // first-conv K padded 74 -> 128
#define ZK 544       // MLP1 K padded 520 -> 544 (17 * 32)
#define DEGCAP 32    // max in-degree bucket (Poisson(4); P(>32) ~ 1e-19)
#define CPITCH 132   // C-tile LDS pitch (u16) for generic gemm epilogue

typedef unsigned short u16;
typedef __attribute__((ext_vector_type(8))) short short8;  // 8 bf16 (4 VGPRs)
typedef __attribute__((ext_vector_type(4))) float f32x4;

__device__ inline u16 f2b(float f) {  // fp32 -> bf16 bits, RNE
    unsigned u = __builtin_bit_cast(unsigned, f);
    u += 0x7fffu + ((u >> 16) & 1u);
    return (u16)(u >> 16);
}
__device__ inline float b2f(u16 b) {
    unsigned u = ((unsigned)b) << 16;
    return __builtin_bit_cast(float, u);
}
__device__ inline float blo(unsigned u) { return __builtin_bit_cast(float, u << 16); }
__device__ inline float bhi(unsigned u) { return __builtin_bit_cast(float, u & 0xffff0000u); }

// ---------- degree count + bucket fill ----------
__global__ void fill_kernel(const int* __restrict__ src, const int* __restrict__ dst,
                            int* __restrict__ dego, int* __restrict__ cnti,
                            int* __restrict__ bucket) {
    int e = blockIdx.x * 256 + threadIdx.x;
    if (e < NE) {
        int s = src[e], d = dst[e];
        atomicAdd(&dego[s], 1);
        int p = atomicAdd(&cnti[d], 1);
        if (p < DEGCAP) bucket[d * DEGCAP + p] = s;
    }
}

__global__ void rsqrt_kernel(const int* __restrict__ dego, const int* __restrict__ cnti,
                             float* __restrict__ rso, float* __restrict__ rsi) {
    int i = blockIdx.x * 256 + threadIdx.x;
    if (i < NN) {
        rso[i] = rsqrtf((float)(dego[i] > 1 ? dego[i] : 1));
        rsi[i] = rsqrtf((float)(cnti[i] > 1 ? cnti[i] : 1));
    }
}

// ---------- pre-scale x rows by rso, cast to bf16 ----------
__global__ __launch_bounds__(128) void prescale_x_kernel(
        const float* __restrict__ x, const float* __restrict__ rso,
        u16* __restrict__ xb) {
    int node = blockIdx.x;
    int f = threadIdx.x;
    if (f < INDIM) {
        float w = rso[node];
        xb[(size_t)node * INDIM + f] = f2b(x[(size_t)node * INDIM + f] * w);
    }
}

// ---------- first-conv aggregation over prescaled bf16 x ----------
__global__ __launch_bounds__(128) void gather_x_kernel(
        const u16* __restrict__ xb, const int* __restrict__ bucket,
        const int* __restrict__ cnti, const float* __restrict__ rsi,
        u16* __restrict__ out) {
    int node = blockIdx.x;
    int f = threadIdx.x;
    int deg = cnti[node]; if (deg > DEGCAP) deg = DEGCAP;
    const int* bk = bucket + node * DEGCAP;
    float acc = 0.f;
    if (f < INDIM) {
        for (int base = 0; base < deg; base += 4) {
            int i0 = bk[base];
            int i1 = (base + 1 < deg) ? bk[base + 1] : i0;  // dup -> broadcast, free
            int i2 = (base + 2 < deg) ? bk[base + 2] : i0;
            int i3 = (base + 3 < deg) ? bk[base + 3] : i0;
            float m1 = (base + 1 < deg) ? 1.f : 0.f;
            float m2 = (base + 2 < deg) ? 1.f : 0.f;
            float m3 = (base + 3 < deg) ? 1.f : 0.f;
            float v0 = b2f(xb[(size_t)i0 * INDIM + f]);
            float v1 = b2f(xb[(size_t)i1 * INDIM + f]);
            float v2 = b2f(xb[(size_t)i2 * INDIM + f]);
            float v3 = b2f(xb[(size_t)i3 * INDIM + f]);
            acc += v0 + m1 * v1 + m2 * v2 + m3 * v3;
        }
    }
    out[(size_t)node * KPAD + f] = f2b(acc * rsi[node]);
}

// ---------- weight prep: fp32 row-major -> bf16 transposed (N-major, K-contig) ----------
__global__ void prep_w0_kernel(const float* __restrict__ W0, u16* __restrict__ Wt0) {
    int i = blockIdx.x * 256 + threadIdx.x;  // 256*128
    int n = i >> 7, k = i & 127;
    float v = (k < INDIM) ? W0[(size_t)k * H + n] : 0.f;
    Wt0[i] = f2b(v);
}

__global__ void prep_gcr_kernel(const float* __restrict__ W, u16* __restrict__ Wt) {
    int i = blockIdx.x * 256 + threadIdx.x;  // 65536 per layer
    int l = blockIdx.y;                      // 0..9
    int n = i >> 8, k = i & 255;
    Wt[(size_t)l * 65536 + i] = f2b(W[(size_t)l * 65536 + (size_t)k * H + n]);
}

__global__ void prep_w1_kernel(const float* __restrict__ W, u16* __restrict__ Wt) {
    int i = blockIdx.x * 256 + threadIdx.x;  // 1024 * 544
    if (i >= 1024 * ZK) return;
    int n = i / ZK, k = i - n * ZK;
    float v = (k < 520) ? W[(size_t)k * 1024 + n] : 0.f;
    Wt[i] = f2b(v);
}

__global__ void prep_w2_kernel(const float* __restrict__ W, u16* __restrict__ Wt) {
    int i = blockIdx.x * 256 + threadIdx.x;  // 512 * 1024
    int n = i >> 10, k = i & 1023;
    Wt[i] = f2b(W[(size_t)k * 512 + n]);
}

// ---------- bf16 MFMA GEMM helpers ----------
__device__ inline void ldg_lds16(const u16* g, u16* l) {
    __builtin_amdgcn_global_load_lds(
        (const __attribute__((address_space(1))) unsigned int*)g,
        (__attribute__((address_space(3))) unsigned int*)l, 16, 0, 0);
}
__device__ inline float actf(float v, int act) {
    if (act == 1) return fmaxf(v, 0.f);
    if (act == 2) return (v > 0.f) ? v : 0.01f * v;
    return v;
}

// ---------- FUSED conv layer: hout = relu( (S.h) @ Wt^T + bias ) ----------
// S.h gathered on the fly into swizzled LDS A-tile (128 x 256 bf16, 64 KB).
// BM=128, BN=256(=H), K=256. Bs: 256x32 (16 KB). Total LDS 80 KB -> 2 blk/CU.
__global__ __launch_bounds__(256) void conv_fused_kernel(
        const u16* __restrict__ h, const int* __restrict__ bucket,
        const int* __restrict__ cnti, const float* __restrict__ rso,
        const float* __restrict__ rsi, const u16* __restrict__ Wt,
        const float* __restrict__ bias, u16* __restrict__ hout) {
    __shared__ __align__(16) u16 Asm[128 * 256];  // 64 KB, XOR-swizzled segs
    __shared__ __align__(16) u16 Bs[256 * 32];    // 16 KB
    int t = threadIdx.x;
    int r0 = blockIdx.x * 128;

    // ---- phase 1: gather A-tile (aggregate neighbors, both norms folded)
    for (int rep = 0; rep < 16; ++rep) {
        int lr = rep * 8 + (t >> 5);      // local row 0..127
        int node = r0 + lr;
        int fc = (t & 31) * 8;            // 8 bf16 = 16 B per thread
        int deg = cnti[node]; if (deg > DEGCAP) deg = DEGCAP;
        const int* bk = bucket + node * DEGCAP;
        float acc[8] = {};
        for (int base = 0; base < deg; base += 4) {
            int i0 = bk[base];
            int i1 = (base + 1 < deg) ? bk[base + 1] : i0;
            int i2 = (base + 2 < deg) ? bk[base + 2] : i0;
            int i3 = (base + 3 < deg) ? bk[base + 3] : i0;
            float w0 = rso[i0];
            float w1 = (base + 1 < deg) ? rso[i1] : 0.f;
            float w2 = (base + 2 < deg) ? rso[i2] : 0.f;
            float w3 = (base + 3 < deg) ? rso[i3] : 0.f;
            uint4 v0 = *(const uint4*)(h + (size_t)i0 * H + fc);
            uint4 v1 = *(const uint4*)(h + (size_t)i1 * H + fc);
            uint4 v2 = *(const uint4*)(h + (size_t)i2 * H + fc);
            uint4 v3 = *(const uint4*)(h + (size_t)i3 * H + fc);
            acc[0] += blo(v0.x) * w0 + blo(v1.x) * w1 + blo(v2.x) * w2 + blo(v3.x) * w3;
            acc[1] += bhi(v0.x) * w0 + bhi(v1.x) * w1 + bhi(v2.x) * w2 + bhi(v3.x) * w3;
            acc[2] += blo(v0.y) * w0 + blo(v1.y) * w1 + blo(v2.y) * w2 + blo(v3.y) * w3;
            acc[3] += bhi(v0.y) * w0 + bhi(v1.y) * w1 + bhi(v2.y) * w2 + bhi(v3.y) * w3;
            acc[4] += blo(v0.z) * w0 + blo(v1.z) * w1 + blo(v2.z) * w2 + blo(v3.z) * w3;
            acc[5] += bhi(v0.z) * w0 + bhi(v1.z) * w1 + bhi(v2.z) * w2 + bhi(v3.z) * w3;
            acc[6] += blo(v0.w) * w0 + blo(v1.w) * w1 + blo(v2.w) * w2 + blo(v3.w) * w3;
            acc[7] += bhi(v0.w) * w0 + bhi(v1.w) * w1 + bhi(v2.w) * w2 + bhi(v3.w) * w3;
        }
        float ri = rsi[node];
        u16 o[8];
#pragma unroll
        for (int i = 0; i < 8; ++i) o[i] = f2b(acc[i] * ri);
        uint4 ov;
        ov.x = o[0] | ((unsigned)o[1] << 16);
        ov.y = o[2] | ((unsigned)o[3] << 16);
        ov.z = o[4] | ((unsigned)o[5] << 16);
        ov.w = o[6] | ((unsigned)o[7] << 16);
        int seg = (t & 31) ^ (lr & 7);    // XOR swizzle: conflict-free banks
        *(uint4*)(Asm + lr * 256 + seg * 8) = ov;
    }
    __syncthreads();

    // ---- phase 2: 128x256 MFMA GEMM, A from LDS, B streamed
    int wave = t >> 6, lane = t & 63;
    int wr = wave >> 1, wc = wave & 1;    // 2x2 waves over 128x256
    int mrow = lane & 15;
    int q = lane >> 4;                    // 0..3
    int r = t >> 2;                       // 0..63 staging row
    int kq = (t & 3) * 8;
    const u16* Bg = Wt + (size_t)r * H + kq;
    u16* BsW = Bs + wave * 512;           // wave-uniform base (HW adds lane*16)

    f32x4 acc[4][8] = {};
    for (int kt = 0; kt < 8; ++kt) {
        ldg_lds16(Bg, BsW);
        ldg_lds16(Bg + (size_t)64 * H, BsW + 2048);
        ldg_lds16(Bg + (size_t)128 * H, BsW + 4096);
        ldg_lds16(Bg + (size_t)192 * H, BsW + 6144);
        __syncthreads();
        short8 a[4], b[8];
#pragma unroll
        for (int mt = 0; mt < 4; ++mt) {
            int row = wr * 64 + mt * 16 + mrow;
            int seg = (kt * 4 + q) ^ (mrow & 7);
            a[mt] = *(const short8*)(Asm + row * 256 + seg * 8);
        }
#pragma unroll
        for (int nt = 0; nt < 8; ++nt)
            b[nt] = *(const short8*)(Bs + (size_t)(wc * 128 + nt * 16 + mrow) * 32 + q * 8);
#pragma unroll
        for (int mt = 0; mt < 4; ++mt)
#pragma unroll
            for (int nt = 0; nt < 8; ++nt)
                acc[mt][nt] = __builtin_amdgcn_mfma_f32_16x16x32_bf16(
                    a[mt], b[nt], acc[mt][nt], 0, 0, 0);
        __syncthreads();
        Bg += 32;
    }

    // ---- epilogue: relu+bias, stage in Asm (linear), coalesced dwordx4 out
    // C/D layout: col=lane&15, row=(lane>>4)*4+reg (m89-verified)
#pragma unroll
    for (int mt = 0; mt < 4; ++mt) {
        int rl = wr * 64 + mt * 16 + q * 4;
#pragma unroll
        for (int nt = 0; nt < 8; ++nt) {
            int cl = wc * 128 + nt * 16 + mrow;
            float bv = bias[cl];
#pragma unroll
            for (int qq = 0; qq < 4; ++qq) {
                float v = fmaxf(acc[mt][nt][qq] + bv, 0.f);
                Asm[(size_t)(rl + qq) * 256 + cl] = f2b(v);
            }
        }
    }
    __syncthreads();
#pragma unroll
    for (int p = 0; p < 16; ++p) {
        int row = p * 8 + (t >> 5);
        int cu = (t & 31) * 8;
        uint4 val = *(const uint4*)(Asm + (size_t)row * 256 + cu);
        *(uint4*)(hout + (size_t)(r0 + row) * H + cu) = val;
    }
}

// ---------- generic 128x128 MFMA GEMM (first conv + MLP head) ----------
__global__ __launch_bounds__(256) void gemm_mfma_kernel(
        const u16* __restrict__ A, int lda,
        const u16* __restrict__ Bt, int ldb,
        const float* __restrict__ bias, u16* __restrict__ C, int ldc,
        int Kiters, int act) {
    __shared__ __align__(16) u16 smem[128 * CPITCH];  // 33 KB; overlays As/Bs
    u16* As = smem;
    u16* Bs = smem + 4096;
    int t = threadIdx.x;
    int wave = t >> 6, lane = t & 63;
    int wr = wave >> 1, wc = wave & 1;
    int row0 = blockIdx.x * 128, col0 = blockIdx.y * 128;

    int r = t >> 2;
    int kq = (t & 3) * 8;
    const u16* Ag0 = A + (size_t)(row0 + r) * lda + kq;
    const u16* Ag1 = A + (size_t)(row0 + 64 + r) * lda + kq;
    const u16* Bg0 = Bt + (size_t)(col0 + r) * ldb + kq;
    const u16* Bg1 = Bt + (size_t)(col0 + 64 + r) * ldb + kq;
    u16* AsW = As + wave * 512;
    u16* BsW = Bs + wave * 512;

    f32x4 acc[4][4] = {};
    int mrow = lane & 15;
    int koff = (lane >> 4) * 8;

    for (int kt = 0; kt < Kiters; ++kt) {
        ldg_lds16(Ag0, AsW);
        ldg_lds16(Ag1, AsW + 2048);
        ldg_lds16(Bg0, BsW);
        ldg_lds16(Bg1, BsW + 2048);
        __syncthreads();
        short8 a[4], b[4];
#pragma unroll
        for (int mt = 0; mt < 4; ++mt)
            a[mt] = *(const short8*)(As + (size_t)(wr * 64 + mt * 16 + mrow) * 32 + koff);
#pragma unroll
        for (int nt = 0; nt < 4; ++nt)
            b[nt] = *(const short8*)(Bs + (size_t)(wc * 64 + nt * 16 + mrow) * 32 + koff);
#pragma unroll
        for (int mt = 0; mt < 4; ++mt)
#pragma unroll
            for (int nt = 0; nt < 4; ++nt)
                acc[mt][nt] = __builtin_amdgcn_mfma_f32_16x16x32_bf16(
                    a[mt], b[nt], acc[mt][nt], 0, 0, 0);
        __syncthreads();
        Ag0 += 32; Ag1 += 32; Bg0 += 32; Bg1 += 32;
    }

#pragma unroll
    for (int mt = 0; mt < 4; ++mt) {
        int rl = wr * 64 + mt * 16 + (lane >> 4) * 4;
#pragma unroll
        for (int nt = 0; nt < 4; ++nt) {
            int cl = wc * 64 + nt * 16 + (lane & 15);
            float bv = bias[col0 + cl];
#pragma unroll
            for (int q = 0; q < 4; ++q) {
                float v = actf(acc[mt][nt][q] + bv, act);
                smem[(size_t)(rl + q) * CPITCH + cl] = f2b(v);
            }
        }
    }
    __syncthreads();
    int rr = t >> 4;
    int seg = t & 15;
#pragma unroll
    for (int pass = 0; pass < 8; ++pass) {
        int row = pass * 16 + rr;
        uint4 val = *(const uint4*)(smem + (size_t)row * CPITCH + seg * 8);
        *(uint4*)(C + (size_t)(row0 + row) * ldc + col0 + seg * 8) = val;
    }
}

// ---------- pooling: sum 40 bf16 rows -> bf16 z (stride ZK) ----------
__global__ __launch_bounds__(256) void pool_kernel(const u16* __restrict__ h,
                                                   u16* __restrict__ z, int zoff) {
    int g = blockIdx.x, f = threadIdx.x;
    float acc = 0.f;
    const u16* base = h + (size_t)g * 40 * H + f;
#pragma unroll
    for (int j = 0; j < 40; ++j) acc += b2f(base[j * H]);
    z[(size_t)g * ZK + zoff + f] = f2b(acc);
}

__global__ void copy_add_kernel(const float* __restrict__ add, u16* __restrict__ z) {
    int i = blockIdx.x * 256 + threadIdx.x;
    if (i < NB * 8) {
        int g = i >> 3, a = i & 7;
        z[(size_t)g * ZK + 512 + a] = f2b(add[i]);
    }
}

// ---------- final GEMV: out[r] = sum_k m2b[r,k]*w[k] + b ----------
__global__ void gemv_out_kernel(const u16* __restrict__ A, const float* __restrict__ w,
                                const float* __restrict__ b, float* __restrict__ out, int K) {
    int wave = threadIdx.x >> 6;
    int lane = threadIdx.x & 63;
    int row = blockIdx.x * 4 + wave;
    float acc = 0.f;
    for (int k = lane; k < K; k += 64) acc += b2f(A[(size_t)row * K + k]) * w[k];
#pragma unroll
    for (int off = 32; off > 0; off >>= 1) acc += __shfl_down(acc, off, 64);
    if (lane == 0) out[row] = acc + b[0];
}

extern "C" void kernel_launch(void* const* d_in, const int* in_sizes, int n_in,
                              void* d_out, int out_size, void* d_ws, size_t ws_size,
                              hipStream_t stream) {
    const int*   cat_src = (const int*)d_in[0];
    const int*   cat_dst = (const int*)d_in[1];
    const float* cat_x   = (const float*)d_in[3];
    const int*   an_src  = (const int*)d_in[4];
    const int*   an_dst  = (const int*)d_in[5];
    const float* an_x    = (const float*)d_in[7];
    const float* add_f   = (const float*)d_in[8];
    const float* W0      = (const float*)d_in[9];
    const float* b0      = (const float*)d_in[10];
    const float* gcrW    = (const float*)d_in[11];
    const float* gcrb    = (const float*)d_in[12];
    const float* mW1     = (const float*)d_in[13];
    const float* mb1     = (const float*)d_in[14];
    const float* mW2     = (const float*)d_in[15];
    const float* mb2     = (const float*)d_in[16];
    const float* mW3     = (const float*)d_in[17];
    const float* mb3     = (const float*)d_in[18];
    float* out = (float*)d_out;

    // ---- workspace carve (~150 MB) ----
    char* p = (char*)d_ws;
    auto alloc = [&](size_t bytes) -> void* {
        void* rp = (void*)p;
        p += (bytes + 255) & ~(size_t)255;
        return rp;
    };
    int*   dego   = (int*)alloc((size_t)NN * 4);
    int*   cnti   = (int*)alloc((size_t)NN * 4);
    int*   bucket = (int*)alloc((size_t)NN * DEGCAP * 4);
    float* rso    = (float*)alloc((size_t)NN * 4);
    float* rsi    = (float*)alloc((size_t)NN * 4);
    u16*   xb     = (u16*)alloc((size_t)NN * INDIM * 2);
    u16*   aggx   = (u16*)alloc((size_t)NN * KPAD * 2);
    u16*   hA     = (u16*)alloc((size_t)NN * H * 2);
    u16*   hB     = (u16*)alloc((size_t)NN * H * 2);
    u16*   Wt0    = (u16*)alloc((size_t)H * KPAD * 2);
    u16*   Wtg    = (u16*)alloc((size_t)10 * H * H * 2);
    u16*   Wt1    = (u16*)alloc((size_t)1024 * ZK * 2);
    u16*   Wt2    = (u16*)alloc((size_t)512 * 1024 * 2);
    u16*   zb     = (u16*)alloc((size_t)NB * ZK * 2);
    u16*   m1b    = (u16*)alloc((size_t)NB * 1024 * 2);
    u16*   m2b    = (u16*)alloc((size_t)NB * 512 * 2);
    (void)ws_size; (void)in_sizes; (void)n_in; (void)out_size;

    // weight prep (bf16 transposed)
    prep_w0_kernel<<<(H * KPAD) / 256, 256, 0, stream>>>(W0, Wt0);
    prep_gcr_kernel<<<dim3(H * H / 256, 10), 256, 0, stream>>>(gcrW, Wtg);
    prep_w1_kernel<<<(1024 * ZK + 255) / 256, 256, 0, stream>>>(mW1, Wt1);
    prep_w2_kernel<<<(512 * 1024) / 256, 256, 0, stream>>>(mW2, Wt2);
    hipMemsetAsync(zb, 0, (size_t)NB * ZK * 2, stream);  // zero K-pad cols

    auto run_side = [&](const int* src, const int* dst, const float* x, int zoff) {
        hipMemsetAsync(dego, 0, (size_t)NN * 4, stream);
        hipMemsetAsync(cnti, 0, (size_t)NN * 4, stream);
        fill_kernel<<<(NE + 255) / 256, 256, 0, stream>>>(src, dst, dego, cnti, bucket);
        rsqrt_kernel<<<NN / 256, 256, 0, stream>>>(dego, cnti, rso, rsi);

        prescale_x_kernel<<<NN, 128, 0, stream>>>(x, rso, xb);
        gather_x_kernel<<<NN, 128, 0, stream>>>(xb, bucket, cnti, rsi, aggx);
        gemm_mfma_kernel<<<dim3(NN / 128, H / 128), 256, 0, stream>>>(
            aggx, KPAD, Wt0, KPAD, b0, hA, H, KPAD / 32, 0);

        // 10 fused conv layers, ping-pong hA <-> hB (ends in hA)
        for (int l = 0; l < 10; ++l) {
            const u16* hin = (l & 1) ? hB : hA;
            u16* hout = (l & 1) ? hA : hB;
            conv_fused_kernel<<<NN / 128, 256, 0, stream>>>(
                hin, bucket, cnti, rso, rsi, Wtg + (size_t)l * H * H,
                gcrb + (size_t)l * H, hout);
        }
        pool_kernel<<<NB, 256, 0, stream>>>(hA, zb, zoff);
    };

    run_side(cat_src, cat_dst, cat_x, 0);
    run_side(an_src, an_dst, an_x, H);
    copy_add_kernel<<<(NB * 8 + 255) / 256, 256, 0, stream>>>(add_f, zb);

    // MLP head (bf16 MFMA)
    gemm_mfma_kernel<<<dim3(NB / 128, 1024 / 128), 256, 0, stream>>>(
        zb, ZK, Wt1, ZK, mb1, m1b, 1024, ZK / 32, 2);
    gemm_mfma_kernel<<<dim3(NB / 128, 512 / 128), 256, 0, stream>>>(
        m1b, 1024, Wt2, 1024, mb2, m2b, 512, 1024 / 32, 2);
    gemv_out_kernel<<<NB / 4, 256, 0, stream>>>(m2b, mW3, mb3, out, 512);
}

// Round 7
// 1878.764 us; speedup vs baseline: 1.6054x; 1.6054x over previous
//
#include <hip/hip_runtime.h>

// SolvGNNV6 round 7: fused gather+GEMM conv v2 — BM=64 (32 KB LDS, 4 blk/CU),
// B-fragments direct from global (no K-loop barriers), XOR-swizzled A-tile.
// Rest identical to round-5 best (1698 us).

#define NN 81920     // nodes
#define NE 327680    // edges
#define NB 2048      // graphs
#define H 256
#define INDIM 74
#define KPAD 128     // first-conv K padded 74 -> 128
#define ZK 544       // MLP1 K padded 520 -> 544 (17 * 32)
#define DEGCAP 32    // max in-degree bucket (Poisson(4); P(>32) ~ 1e-19)
#define CPITCH 132   // C-tile LDS pitch (u16) for generic gemm epilogue

typedef unsigned short u16;
typedef __attribute__((ext_vector_type(8))) short short8;  // 8 bf16 (4 VGPRs)
typedef __attribute__((ext_vector_type(4))) float f32x4;

__device__ inline u16 f2b(float f) {  // fp32 -> bf16 bits, RNE
    unsigned u = __builtin_bit_cast(unsigned, f);
    u += 0x7fffu + ((u >> 16) & 1u);
    return (u16)(u >> 16);
}
__device__ inline float b2f(u16 b) {
    unsigned u = ((unsigned)b) << 16;
    return __builtin_bit_cast(float, u);
}
__device__ inline float blo(unsigned u) { return __builtin_bit_cast(float, u << 16); }
__device__ inline float bhi(unsigned u) { return __builtin_bit_cast(float, u & 0xffff0000u); }

// ---------- degree count + bucket fill ----------
__global__ void fill_kernel(const int* __restrict__ src, const int* __restrict__ dst,
                            int* __restrict__ dego, int* __restrict__ cnti,
                            int* __restrict__ bucket) {
    int e = blockIdx.x * 256 + threadIdx.x;
    if (e < NE) {
        int s = src[e], d = dst[e];
        atomicAdd(&dego[s], 1);
        int p = atomicAdd(&cnti[d], 1);
        if (p < DEGCAP) bucket[d * DEGCAP + p] = s;
    }
}

__global__ void rsqrt_kernel(const int* __restrict__ dego, const int* __restrict__ cnti,
                             float* __restrict__ rso, float* __restrict__ rsi) {
    int i = blockIdx.x * 256 + threadIdx.x;
    if (i < NN) {
        rso[i] = rsqrtf((float)(dego[i] > 1 ? dego[i] : 1));
        rsi[i] = rsqrtf((float)(cnti[i] > 1 ? cnti[i] : 1));
    }
}

// ---------- pre-scale x rows by rso, cast to bf16 ----------
__global__ __launch_bounds__(128) void prescale_x_kernel(
        const float* __restrict__ x, const float* __restrict__ rso,
        u16* __restrict__ xb) {
    int node = blockIdx.x;
    int f = threadIdx.x;
    if (f < INDIM) {
        float w = rso[node];
        xb[(size_t)node * INDIM + f] = f2b(x[(size_t)node * INDIM + f] * w);
    }
}

// ---------- first-conv aggregation over prescaled bf16 x ----------
__global__ __launch_bounds__(128) void gather_x_kernel(
        const u16* __restrict__ xb, const int* __restrict__ bucket,
        const int* __restrict__ cnti, const float* __restrict__ rsi,
        u16* __restrict__ out) {
    int node = blockIdx.x;
    int f = threadIdx.x;
    int deg = cnti[node]; if (deg > DEGCAP) deg = DEGCAP;
    const int* bk = bucket + node * DEGCAP;
    float acc = 0.f;
    if (f < INDIM) {
        for (int base = 0; base < deg; base += 4) {
            int i0 = bk[base];
            int i1 = (base + 1 < deg) ? bk[base + 1] : i0;  // dup -> broadcast, free
            int i2 = (base + 2 < deg) ? bk[base + 2] : i0;
            int i3 = (base + 3 < deg) ? bk[base + 3] : i0;
            float m1 = (base + 1 < deg) ? 1.f : 0.f;
            float m2 = (base + 2 < deg) ? 1.f : 0.f;
            float m3 = (base + 3 < deg) ? 1.f : 0.f;
            float v0 = b2f(xb[(size_t)i0 * INDIM + f]);
            float v1 = b2f(xb[(size_t)i1 * INDIM + f]);
            float v2 = b2f(xb[(size_t)i2 * INDIM + f]);
            float v3 = b2f(xb[(size_t)i3 * INDIM + f]);
            acc += v0 + m1 * v1 + m2 * v2 + m3 * v3;
        }
    }
    out[(size_t)node * KPAD + f] = f2b(acc * rsi[node]);
}

// ---------- weight prep: fp32 row-major -> bf16 transposed (N-major, K-contig) ----------
__global__ void prep_w0_kernel(const float* __restrict__ W0, u16* __restrict__ Wt0) {
    int i = blockIdx.x * 256 + threadIdx.x;  // 256*128
    int n = i >> 7, k = i & 127;
    float v = (k < INDIM) ? W0[(size_t)k * H + n] : 0.f;
    Wt0[i] = f2b(v);
}

__global__ void prep_gcr_kernel(const float* __restrict__ W, u16* __restrict__ Wt) {
    int i = blockIdx.x * 256 + threadIdx.x;  // 65536 per layer
    int l = blockIdx.y;                      // 0..9
    int n = i >> 8, k = i & 255;
    Wt[(size_t)l * 65536 + i] = f2b(W[(size_t)l * 65536 + (size_t)k * H + n]);
}

__global__ void prep_w1_kernel(const float* __restrict__ W, u16* __restrict__ Wt) {
    int i = blockIdx.x * 256 + threadIdx.x;  // 1024 * 544
    if (i >= 1024 * ZK) return;
    int n = i / ZK, k = i - n * ZK;
    float v = (k < 520) ? W[(size_t)k * 1024 + n] : 0.f;
    Wt[i] = f2b(v);
}

__global__ void prep_w2_kernel(const float* __restrict__ W, u16* __restrict__ Wt) {
    int i = blockIdx.x * 256 + threadIdx.x;  // 512 * 1024
    int n = i >> 10, k = i & 1023;
    Wt[i] = f2b(W[(size_t)k * 512 + n]);
}

// ---------- bf16 MFMA GEMM helpers ----------
__device__ inline void ldg_lds16(const u16* g, u16* l) {
    __builtin_amdgcn_global_load_lds(
        (const __attribute__((address_space(1))) unsigned int*)g,
        (__attribute__((address_space(3))) unsigned int*)l, 16, 0, 0);
}
__device__ inline float actf(float v, int act) {
    if (act == 1) return fmaxf(v, 0.f);
    if (act == 2) return (v > 0.f) ? v : 0.01f * v;
    return v;
}

// ---------- FUSED conv v2: hout = relu( (S.h) @ Wt^T + bias ) ----------
// BM=64, BN=256(=H), K=256. A-tile 64x256 bf16 (32 KB, XOR-swizzled) gathered
// in-kernel; B fragments loaded straight from global (L1/L2-resident weights).
// No barriers in the K-loop; 3 __syncthreads total. Grid NN/64 = 1280 blocks.
__global__ __launch_bounds__(256) void conv_fused_kernel(
        const u16* __restrict__ h, const int* __restrict__ bucket,
        const int* __restrict__ cnti, const float* __restrict__ rso,
        const float* __restrict__ rsi, const u16* __restrict__ Wt,
        const float* __restrict__ bias, u16* __restrict__ hout) {
    __shared__ __align__(16) u16 Asm[64 * 256];  // 32 KB
    int t = threadIdx.x;
    int r0 = blockIdx.x * 64;

    // ---- phase 1: gather 64 aggregated rows into swizzled LDS
    for (int rep = 0; rep < 8; ++rep) {
        int lr = rep * 8 + (t >> 5);      // local row 0..63
        int node = r0 + lr;
        int fc = (t & 31) * 8;            // 8 bf16 = 16 B per thread
        int deg = cnti[node]; if (deg > DEGCAP) deg = DEGCAP;
        const int* bk = bucket + node * DEGCAP;
        float acc[8] = {};
        for (int base = 0; base < deg; base += 4) {
            int i0 = bk[base];
            int i1 = (base + 1 < deg) ? bk[base + 1] : i0;
            int i2 = (base + 2 < deg) ? bk[base + 2] : i0;
            int i3 = (base + 3 < deg) ? bk[base + 3] : i0;
            float w0 = rso[i0];
            float w1 = (base + 1 < deg) ? rso[i1] : 0.f;
            float w2 = (base + 2 < deg) ? rso[i2] : 0.f;
            float w3 = (base + 3 < deg) ? rso[i3] : 0.f;
            uint4 v0 = *(const uint4*)(h + (size_t)i0 * H + fc);
            uint4 v1 = *(const uint4*)(h + (size_t)i1 * H + fc);
            uint4 v2 = *(const uint4*)(h + (size_t)i2 * H + fc);
            uint4 v3 = *(const uint4*)(h + (size_t)i3 * H + fc);
            acc[0] += blo(v0.x) * w0 + blo(v1.x) * w1 + blo(v2.x) * w2 + blo(v3.x) * w3;
            acc[1] += bhi(v0.x) * w0 + bhi(v1.x) * w1 + bhi(v2.x) * w2 + bhi(v3.x) * w3;
            acc[2] += blo(v0.y) * w0 + blo(v1.y) * w1 + blo(v2.y) * w2 + blo(v3.y) * w3;
            acc[3] += bhi(v0.y) * w0 + bhi(v1.y) * w1 + bhi(v2.y) * w2 + bhi(v3.y) * w3;
            acc[4] += blo(v0.z) * w0 + blo(v1.z) * w1 + blo(v2.z) * w2 + blo(v3.z) * w3;
            acc[5] += bhi(v0.z) * w0 + bhi(v1.z) * w1 + bhi(v2.z) * w2 + bhi(v3.z) * w3;
            acc[6] += blo(v0.w) * w0 + blo(v1.w) * w1 + blo(v2.w) * w2 + blo(v3.w) * w3;
            acc[7] += bhi(v0.w) * w0 + bhi(v1.w) * w1 + bhi(v2.w) * w2 + bhi(v3.w) * w3;
        }
        float ri = rsi[node];
        u16 o[8];
#pragma unroll
        for (int i = 0; i < 8; ++i) o[i] = f2b(acc[i] * ri);
        uint4 ov;
        ov.x = o[0] | ((unsigned)o[1] << 16);
        ov.y = o[2] | ((unsigned)o[3] << 16);
        ov.z = o[4] | ((unsigned)o[5] << 16);
        ov.w = o[6] | ((unsigned)o[7] << 16);
        int seg = (t & 31) ^ (lr & 7);    // XOR swizzle
        *(uint4*)(Asm + lr * 256 + seg * 8) = ov;
    }
    __syncthreads();

    // ---- phase 2: 64x256 MFMA GEMM; A from LDS, B straight from global
    int wave = t >> 6, lane = t & 63;
    int mrow = lane & 15;
    int q = lane >> 4;                    // 0..3
    const u16* bp0 = Wt + (size_t)(wave * 64 + 0 * 16 + mrow) * H + q * 8;
    const u16* bp1 = Wt + (size_t)(wave * 64 + 1 * 16 + mrow) * H + q * 8;
    const u16* bp2 = Wt + (size_t)(wave * 64 + 2 * 16 + mrow) * H + q * 8;
    const u16* bp3 = Wt + (size_t)(wave * 64 + 3 * 16 + mrow) * H + q * 8;

    f32x4 acc[4][4] = {};
#pragma unroll
    for (int kt = 0; kt < 8; ++kt) {
        short8 a[4], b[4];
#pragma unroll
        for (int mt = 0; mt < 4; ++mt) {
            int row = mt * 16 + mrow;
            int seg = (kt * 4 + q) ^ (row & 7);
            a[mt] = *(const short8*)(Asm + row * 256 + seg * 8);
        }
        b[0] = *(const short8*)(bp0); bp0 += 32;
        b[1] = *(const short8*)(bp1); bp1 += 32;
        b[2] = *(const short8*)(bp2); bp2 += 32;
        b[3] = *(const short8*)(bp3); bp3 += 32;
#pragma unroll
        for (int mt = 0; mt < 4; ++mt)
#pragma unroll
            for (int nt = 0; nt < 4; ++nt)
                acc[mt][nt] = __builtin_amdgcn_mfma_f32_16x16x32_bf16(
                    a[mt], b[nt], acc[mt][nt], 0, 0, 0);
    }
    __syncthreads();   // all A-tile reads done; Asm reusable for C staging

    // ---- epilogue: bias+relu -> Asm (row-XOR swizzled segs) -> coalesced out
    // C/D layout: col=lane&15, row=(lane>>4)*4+reg (m89-verified)
#pragma unroll
    for (int mt = 0; mt < 4; ++mt) {
#pragma unroll
        for (int nt = 0; nt < 4; ++nt) {
            int cl = wave * 64 + nt * 16 + mrow;
            float bv = bias[cl];
            int segl = cl >> 3, wi = cl & 7;
#pragma unroll
            for (int qq = 0; qq < 4; ++qq) {
                int row = mt * 16 + q * 4 + qq;
                float v = fmaxf(acc[mt][nt][qq] + bv, 0.f);
                Asm[row * 256 + (segl ^ (row & 7)) * 8 + wi] = f2b(v);
            }
        }
    }
    __syncthreads();
#pragma unroll
    for (int pass = 0; pass < 8; ++pass) {
        int row = pass * 8 + (t >> 5);
        int seg = (t & 31) ^ (row & 7);
        uint4 val = *(const uint4*)(Asm + row * 256 + seg * 8);
        *(uint4*)(hout + (size_t)(r0 + row) * H + (t & 31) * 8) = val;
    }
}

// ---------- generic 128x128 MFMA GEMM (first conv + MLP head) ----------
__global__ __launch_bounds__(256) void gemm_mfma_kernel(
        const u16* __restrict__ A, int lda,
        const u16* __restrict__ Bt, int ldb,
        const float* __restrict__ bias, u16* __restrict__ C, int ldc,
        int Kiters, int act) {
    __shared__ __align__(16) u16 smem[128 * CPITCH];  // 33 KB; overlays As/Bs
    u16* As = smem;
    u16* Bs = smem + 4096;
    int t = threadIdx.x;
    int wave = t >> 6, lane = t & 63;
    int wr = wave >> 1, wc = wave & 1;
    int row0 = blockIdx.x * 128, col0 = blockIdx.y * 128;

    int r = t >> 2;
    int kq = (t & 3) * 8;
    const u16* Ag0 = A + (size_t)(row0 + r) * lda + kq;
    const u16* Ag1 = A + (size_t)(row0 + 64 + r) * lda + kq;
    const u16* Bg0 = Bt + (size_t)(col0 + r) * ldb + kq;
    const u16* Bg1 = Bt + (size_t)(col0 + 64 + r) * ldb + kq;
    u16* AsW = As + wave * 512;
    u16* BsW = Bs + wave * 512;

    f32x4 acc[4][4] = {};
    int mrow = lane & 15;
    int koff = (lane >> 4) * 8;

    for (int kt = 0; kt < Kiters; ++kt) {
        ldg_lds16(Ag0, AsW);
        ldg_lds16(Ag1, AsW + 2048);
        ldg_lds16(Bg0, BsW);
        ldg_lds16(Bg1, BsW + 2048);
        __syncthreads();
        short8 a[4], b[4];
#pragma unroll
        for (int mt = 0; mt < 4; ++mt)
            a[mt] = *(const short8*)(As + (size_t)(wr * 64 + mt * 16 + mrow) * 32 + koff);
#pragma unroll
        for (int nt = 0; nt < 4; ++nt)
            b[nt] = *(const short8*)(Bs + (size_t)(wc * 64 + nt * 16 + mrow) * 32 + koff);
#pragma unroll
        for (int mt = 0; mt < 4; ++mt)
#pragma unroll
            for (int nt = 0; nt < 4; ++nt)
                acc[mt][nt] = __builtin_amdgcn_mfma_f32_16x16x32_bf16(
                    a[mt], b[nt], acc[mt][nt], 0, 0, 0);
        __syncthreads();
        Ag0 += 32; Ag1 += 32; Bg0 += 32; Bg1 += 32;
    }

#pragma unroll
    for (int mt = 0; mt < 4; ++mt) {
        int rl = wr * 64 + mt * 16 + (lane >> 4) * 4;
#pragma unroll
        for (int nt = 0; nt < 4; ++nt) {
            int cl = wc * 64 + nt * 16 + (lane & 15);
            float bv = bias[col0 + cl];
#pragma unroll
            for (int q = 0; q < 4; ++q) {
                float v = actf(acc[mt][nt][q] + bv, act);
                smem[(size_t)(rl + q) * CPITCH + cl] = f2b(v);
            }
        }
    }
    __syncthreads();
    int rr = t >> 4;
    int seg = t & 15;
#pragma unroll
    for (int pass = 0; pass < 8; ++pass) {
        int row = pass * 16 + rr;
        uint4 val = *(const uint4*)(smem + (size_t)row * CPITCH + seg * 8);
        *(uint4*)(C + (size_t)(row0 + row) * ldc + col0 + seg * 8) = val;
    }
}

// ---------- pooling: sum 40 bf16 rows -> bf16 z (stride ZK) ----------
__global__ __launch_bounds__(256) void pool_kernel(const u16* __restrict__ h,
                                                   u16* __restrict__ z, int zoff) {
    int g = blockIdx.x, f = threadIdx.x;
    float acc = 0.f;
    const u16* base = h + (size_t)g * 40 * H + f;
#pragma unroll
    for (int j = 0; j < 40; ++j) acc += b2f(base[j * H]);
    z[(size_t)g * ZK + zoff + f] = f2b(acc);
}

__global__ void copy_add_kernel(const float* __restrict__ add, u16* __restrict__ z) {
    int i = blockIdx.x * 256 + threadIdx.x;
    if (i < NB * 8) {
        int g = i >> 3, a = i & 7;
        z[(size_t)g * ZK + 512 + a] = f2b(add[i]);
    }
}

// ---------- final GEMV: out[r] = sum_k m2b[r,k]*w[k] + b ----------
__global__ void gemv_out_kernel(const u16* __restrict__ A, const float* __restrict__ w,
                                const float* __restrict__ b, float* __restrict__ out, int K) {
    int wave = threadIdx.x >> 6;
    int lane = threadIdx.x & 63;
    int row = blockIdx.x * 4 + wave;
    float acc = 0.f;
    for (int k = lane; k < K; k += 64) acc += b2f(A[(size_t)row * K + k]) * w[k];
#pragma unroll
    for (int off = 32; off > 0; off >>= 1) acc += __shfl_down(acc, off, 64);
    if (lane == 0) out[row] = acc + b[0];
}

extern "C" void kernel_launch(void* const* d_in, const int* in_sizes, int n_in,
                              void* d_out, int out_size, void* d_ws, size_t ws_size,
                              hipStream_t stream) {
    const int*   cat_src = (const int*)d_in[0];
    const int*   cat_dst = (const int*)d_in[1];
    const float* cat_x   = (const float*)d_in[3];
    const int*   an_src  = (const int*)d_in[4];
    const int*   an_dst  = (const int*)d_in[5];
    const float* an_x    = (const float*)d_in[7];
    const float* add_f   = (const float*)d_in[8];
    const float* W0      = (const float*)d_in[9];
    const float* b0      = (const float*)d_in[10];
    const float* gcrW    = (const float*)d_in[11];
    const float* gcrb    = (const float*)d_in[12];
    const float* mW1     = (const float*)d_in[13];
    const float* mb1     = (const float*)d_in[14];
    const float* mW2     = (const float*)d_in[15];
    const float* mb2     = (const float*)d_in[16];
    const float* mW3     = (const float*)d_in[17];
    const float* mb3     = (const float*)d_in[18];
    float* out = (float*)d_out;

    // ---- workspace carve (~150 MB) ----
    char* p = (char*)d_ws;
    auto alloc = [&](size_t bytes) -> void* {
        void* rp = (void*)p;
        p += (bytes + 255) & ~(size_t)255;
        return rp;
    };
    int*   dego   = (int*)alloc((size_t)NN * 4);
    int*   cnti   = (int*)alloc((size_t)NN * 4);
    int*   bucket = (int*)alloc((size_t)NN * DEGCAP * 4);
    float* rso    = (float*)alloc((size_t)NN * 4);
    float* rsi    = (float*)alloc((size_t)NN * 4);
    u16*   xb     = (u16*)alloc((size_t)NN * INDIM * 2);
    u16*   aggx   = (u16*)alloc((size_t)NN * KPAD * 2);
    u16*   hA     = (u16*)alloc((size_t)NN * H * 2);
    u16*   hB     = (u16*)alloc((size_t)NN * H * 2);
    u16*   Wt0    = (u16*)alloc((size_t)H * KPAD * 2);
    u16*   Wtg    = (u16*)alloc((size_t)10 * H * H * 2);
    u16*   Wt1    = (u16*)alloc((size_t)1024 * ZK * 2);
    u16*   Wt2    = (u16*)alloc((size_t)512 * 1024 * 2);
    u16*   zb     = (u16*)alloc((size_t)NB * ZK * 2);
    u16*   m1b    = (u16*)alloc((size_t)NB * 1024 * 2);
    u16*   m2b    = (u16*)alloc((size_t)NB * 512 * 2);
    (void)ws_size; (void)in_sizes; (void)n_in; (void)out_size;

    // weight prep (bf16 transposed)
    prep_w0_kernel<<<(H * KPAD) / 256, 256, 0, stream>>>(W0, Wt0);
    prep_gcr_kernel<<<dim3(H * H / 256, 10), 256, 0, stream>>>(gcrW, Wtg);
    prep_w1_kernel<<<(1024 * ZK + 255) / 256, 256, 0, stream>>>(mW1, Wt1);
    prep_w2_kernel<<<(512 * 1024) / 256, 256, 0, stream>>>(mW2, Wt2);
    hipMemsetAsync(zb, 0, (size_t)NB * ZK * 2, stream);  // zero K-pad cols

    auto run_side = [&](const int* src, const int* dst, const float* x, int zoff) {
        hipMemsetAsync(dego, 0, (size_t)NN * 4, stream);
        hipMemsetAsync(cnti, 0, (size_t)NN * 4, stream);
        fill_kernel<<<(NE + 255) / 256, 256, 0, stream>>>(src, dst, dego, cnti, bucket);
        rsqrt_kernel<<<NN / 256, 256, 0, stream>>>(dego, cnti, rso, rsi);

        prescale_x_kernel<<<NN, 128, 0, stream>>>(x, rso, xb);
        gather_x_kernel<<<NN, 128, 0, stream>>>(xb, bucket, cnti, rsi, aggx);
        gemm_mfma_kernel<<<dim3(NN / 128, H / 128), 256, 0, stream>>>(
            aggx, KPAD, Wt0, KPAD, b0, hA, H, KPAD / 32, 0);

        // 10 fused conv layers, ping-pong hA <-> hB (ends in hA)
        for (int l = 0; l < 10; ++l) {
            const u16* hin = (l & 1) ? hB : hA;
            u16* hout = (l & 1) ? hA : hB;
            conv_fused_kernel<<<NN / 64, 256, 0, stream>>>(
                hin, bucket, cnti, rso, rsi, Wtg + (size_t)l * H * H,
                gcrb + (size_t)l * H, hout);
        }
        pool_kernel<<<NB, 256, 0, stream>>>(hA, zb, zoff);
    };

    run_side(cat_src, cat_dst, cat_x, 0);
    run_side(an_src, an_dst, an_x, H);
    copy_add_kernel<<<(NB * 8 + 255) / 256, 256, 0, stream>>>(add_f, zb);

    // MLP head (bf16 MFMA)
    gemm_mfma_kernel<<<dim3(NB / 128, 1024 / 128), 256, 0, stream>>>(
        zb, ZK, Wt1, ZK, mb1, m1b, 1024, ZK / 32, 2);
    gemm_mfma_kernel<<<dim3(NB / 128, 512 / 128), 256, 0, stream>>>(
        m1b, 1024, Wt2, 1024, mb2, m2b, 512, 1024 / 32, 2);
    gemv_out_kernel<<<NB / 4, 256, 0, stream>>>(m2b, mW3, mb3, out, 512);
}

// Round 8
// 1604.377 us; speedup vs baseline: 1.8799x; 1.1710x over previous
//
#include <hip/hip_runtime.h>

// SolvGNNV6 round 8: merged cation+anion node space (2x size, half the
// dispatches). Round-5 proven kernels throughout; fusion abandoned (r6/r7:
// gather TLP collapses to GEMM parallelism). xb/aggx alias hA/hB dead ranges.

#define NN 81920     // nodes per side
#define NN2 163840   // merged nodes (cat | an+NN)
#define NE 327680    // edges per side
#define NE2 655360
#define NB 2048      // graphs per side
#define NB2 4096
#define H 256
#define INDIM 74
#define KPAD 128     // first-conv K padded 74 -> 128
#define ZK 544       // MLP1 K padded 520 -> 544 (17 * 32)
#define DEGCAP 32    // max in-degree bucket (Poisson(4); P(>32) ~ 1e-19)
#define CPITCH 132   // C-tile LDS pitch (u16) for gemm epilogue

typedef unsigned short u16;
typedef __attribute__((ext_vector_type(8))) short short8;  // 8 bf16 (4 VGPRs)
typedef __attribute__((ext_vector_type(4))) float f32x4;

__device__ inline u16 f2b(float f) {  // fp32 -> bf16 bits, RNE
    unsigned u = __builtin_bit_cast(unsigned, f);
    u += 0x7fffu + ((u >> 16) & 1u);
    return (u16)(u >> 16);
}
__device__ inline float b2f(u16 b) {
    unsigned u = ((unsigned)b) << 16;
    return __builtin_bit_cast(float, u);
}
__device__ inline float blo(unsigned u) { return __builtin_bit_cast(float, u << 16); }
__device__ inline float bhi(unsigned u) { return __builtin_bit_cast(float, u & 0xffff0000u); }

// ---------- merged degree count + bucket fill (both sides, one pass) ----------
__global__ void fill_kernel(const int* __restrict__ cs, const int* __restrict__ cd,
                            const int* __restrict__ as_, const int* __restrict__ ad,
                            int* __restrict__ dego, int* __restrict__ cnti,
                            int* __restrict__ bucket) {
    int e = blockIdx.x * 256 + threadIdx.x;
    if (e < NE2) {
        int s, d;
        if (e < NE) { s = cs[e]; d = cd[e]; }
        else        { s = as_[e - NE] + NN; d = ad[e - NE] + NN; }
        atomicAdd(&dego[s], 1);
        int p = atomicAdd(&cnti[d], 1);
        if (p < DEGCAP) bucket[d * DEGCAP + p] = s;
    }
}

__global__ void rsqrt_kernel(const int* __restrict__ dego, const int* __restrict__ cnti,
                             float* __restrict__ rso, float* __restrict__ rsi) {
    int i = blockIdx.x * 256 + threadIdx.x;
    if (i < NN2) {
        rso[i] = rsqrtf((float)(dego[i] > 1 ? dego[i] : 1));
        rsi[i] = rsqrtf((float)(cnti[i] > 1 ? cnti[i] : 1));
    }
}

// ---------- pre-scale x rows by rso, cast to bf16 (merged sides) ----------
__global__ __launch_bounds__(128) void prescale_x_kernel(
        const float* __restrict__ cx, const float* __restrict__ ax,
        const float* __restrict__ rso, u16* __restrict__ xb) {
    int node = blockIdx.x;
    int f = threadIdx.x;
    if (f < INDIM) {
        const float* x = (node < NN) ? (cx + (size_t)node * INDIM)
                                     : (ax + (size_t)(node - NN) * INDIM);
        xb[(size_t)node * INDIM + f] = f2b(x[f] * rso[node]);
    }
}

// ---------- first-conv aggregation over prescaled bf16 x ----------
__global__ __launch_bounds__(128) void gather_x_kernel(
        const u16* __restrict__ xb, const int* __restrict__ bucket,
        const int* __restrict__ cnti, const float* __restrict__ rsi,
        u16* __restrict__ out) {
    int node = blockIdx.x;
    int f = threadIdx.x;
    int deg = cnti[node]; if (deg > DEGCAP) deg = DEGCAP;
    const int* bk = bucket + node * DEGCAP;
    float acc = 0.f;
    if (f < INDIM) {
        for (int base = 0; base < deg; base += 4) {
            int i0 = bk[base];
            int i1 = (base + 1 < deg) ? bk[base + 1] : i0;  // dup -> broadcast, free
            int i2 = (base + 2 < deg) ? bk[base + 2] : i0;
            int i3 = (base + 3 < deg) ? bk[base + 3] : i0;
            float m1 = (base + 1 < deg) ? 1.f : 0.f;
            float m2 = (base + 2 < deg) ? 1.f : 0.f;
            float m3 = (base + 3 < deg) ? 1.f : 0.f;
            float v0 = b2f(xb[(size_t)i0 * INDIM + f]);
            float v1 = b2f(xb[(size_t)i1 * INDIM + f]);
            float v2 = b2f(xb[(size_t)i2 * INDIM + f]);
            float v3 = b2f(xb[(size_t)i3 * INDIM + f]);
            acc += v0 + m1 * v1 + m2 * v2 + m3 * v3;
        }
    }
    out[(size_t)node * KPAD + f] = f2b(acc * rsi[node]);
}

// ---------- H-dim aggregation, 4-wide neighbor batching (merged) ----------
__global__ __launch_bounds__(256) void gather_h_kernel(
        const u16* __restrict__ h, const int* __restrict__ bucket,
        const int* __restrict__ cnti, const float* __restrict__ rso,
        const float* __restrict__ rsi, u16* __restrict__ out) {
    int node = blockIdx.x * 8 + (threadIdx.x >> 5);
    int fc = (threadIdx.x & 31) * 8;     // 8 bf16 = 16 B per thread
    int deg = cnti[node]; if (deg > DEGCAP) deg = DEGCAP;
    const int* bk = bucket + node * DEGCAP;
    float acc[8] = {};
    for (int base = 0; base < deg; base += 4) {
        int i0 = bk[base];
        int i1 = (base + 1 < deg) ? bk[base + 1] : i0;
        int i2 = (base + 2 < deg) ? bk[base + 2] : i0;
        int i3 = (base + 3 < deg) ? bk[base + 3] : i0;
        float w0 = rso[i0];
        float w1 = (base + 1 < deg) ? rso[i1] : 0.f;
        float w2 = (base + 2 < deg) ? rso[i2] : 0.f;
        float w3 = (base + 3 < deg) ? rso[i3] : 0.f;
        uint4 v0 = *(const uint4*)(h + (size_t)i0 * H + fc);
        uint4 v1 = *(const uint4*)(h + (size_t)i1 * H + fc);
        uint4 v2 = *(const uint4*)(h + (size_t)i2 * H + fc);
        uint4 v3 = *(const uint4*)(h + (size_t)i3 * H + fc);
        acc[0] += blo(v0.x) * w0 + blo(v1.x) * w1 + blo(v2.x) * w2 + blo(v3.x) * w3;
        acc[1] += bhi(v0.x) * w0 + bhi(v1.x) * w1 + bhi(v2.x) * w2 + bhi(v3.x) * w3;
        acc[2] += blo(v0.y) * w0 + blo(v1.y) * w1 + blo(v2.y) * w2 + blo(v3.y) * w3;
        acc[3] += bhi(v0.y) * w0 + bhi(v1.y) * w1 + bhi(v2.y) * w2 + bhi(v3.y) * w3;
        acc[4] += blo(v0.z) * w0 + blo(v1.z) * w1 + blo(v2.z) * w2 + blo(v3.z) * w3;
        acc[5] += bhi(v0.z) * w0 + bhi(v1.z) * w1 + bhi(v2.z) * w2 + bhi(v3.z) * w3;
        acc[6] += blo(v0.w) * w0 + blo(v1.w) * w1 + blo(v2.w) * w2 + blo(v3.w) * w3;
        acc[7] += bhi(v0.w) * w0 + bhi(v1.w) * w1 + bhi(v2.w) * w2 + bhi(v3.w) * w3;
    }
    float ri = rsi[node];
    u16 o[8];
#pragma unroll
    for (int i = 0; i < 8; ++i) o[i] = f2b(acc[i] * ri);
    uint4 ov;
    ov.x = o[0] | ((unsigned)o[1] << 16);
    ov.y = o[2] | ((unsigned)o[3] << 16);
    ov.z = o[4] | ((unsigned)o[5] << 16);
    ov.w = o[6] | ((unsigned)o[7] << 16);
    *(uint4*)(out + (size_t)node * H + fc) = ov;
}

// ---------- weight prep: fp32 row-major -> bf16 transposed ----------
__global__ void prep_w0_kernel(const float* __restrict__ W0, u16* __restrict__ Wt0) {
    int i = blockIdx.x * 256 + threadIdx.x;  // 256*128
    int n = i >> 7, k = i & 127;
    float v = (k < INDIM) ? W0[(size_t)k * H + n] : 0.f;
    Wt0[i] = f2b(v);
}

__global__ void prep_gcr_kernel(const float* __restrict__ W, u16* __restrict__ Wt) {
    int i = blockIdx.x * 256 + threadIdx.x;  // 65536 per layer
    int l = blockIdx.y;                      // 0..9
    int n = i >> 8, k = i & 255;
    Wt[(size_t)l * 65536 + i] = f2b(W[(size_t)l * 65536 + (size_t)k * H + n]);
}

__global__ void prep_w1_kernel(const float* __restrict__ W, u16* __restrict__ Wt) {
    int i = blockIdx.x * 256 + threadIdx.x;  // 1024 * 544
    if (i >= 1024 * ZK) return;
    int n = i / ZK, k = i - n * ZK;
    float v = (k < 520) ? W[(size_t)k * 1024 + n] : 0.f;
    Wt[i] = f2b(v);
}

__global__ void prep_w2_kernel(const float* __restrict__ W, u16* __restrict__ Wt) {
    int i = blockIdx.x * 256 + threadIdx.x;  // 512 * 1024
    int n = i >> 10, k = i & 1023;
    Wt[i] = f2b(W[(size_t)k * 512 + n]);
}

// ---------- bf16 MFMA GEMM helpers ----------
__device__ inline void ldg_lds16(const u16* g, u16* l) {
    __builtin_amdgcn_global_load_lds(
        (const __attribute__((address_space(1))) unsigned int*)g,
        (__attribute__((address_space(3))) unsigned int*)l, 16, 0, 0);
}
__device__ inline float actf(float v, int act) {
    if (act == 1) return fmaxf(v, 0.f);
    if (act == 2) return (v > 0.f) ? v : 0.01f * v;
    return v;
}

// ---------- 128x128 MFMA GEMM: C = act(A @ Bt^T + bias), BK=32 ----------
__global__ __launch_bounds__(256) void gemm_mfma_kernel(
        const u16* __restrict__ A, int lda,
        const u16* __restrict__ Bt, int ldb,
        const float* __restrict__ bias, u16* __restrict__ C, int ldc,
        int Kiters, int act) {
    __shared__ __align__(16) u16 smem[128 * CPITCH];  // 33 KB; overlays As/Bs
    u16* As = smem;
    u16* Bs = smem + 4096;
    int t = threadIdx.x;
    int wave = t >> 6, lane = t & 63;
    int wr = wave >> 1, wc = wave & 1;
    int row0 = blockIdx.x * 128, col0 = blockIdx.y * 128;

    int r = t >> 2;
    int kq = (t & 3) * 8;
    const u16* Ag0 = A + (size_t)(row0 + r) * lda + kq;
    const u16* Ag1 = A + (size_t)(row0 + 64 + r) * lda + kq;
    const u16* Bg0 = Bt + (size_t)(col0 + r) * ldb + kq;
    const u16* Bg1 = Bt + (size_t)(col0 + 64 + r) * ldb + kq;
    u16* AsW = As + wave * 512;
    u16* BsW = Bs + wave * 512;

    f32x4 acc[4][4] = {};
    int mrow = lane & 15;
    int koff = (lane >> 4) * 8;

    for (int kt = 0; kt < Kiters; ++kt) {
        ldg_lds16(Ag0, AsW);
        ldg_lds16(Ag1, AsW + 2048);
        ldg_lds16(Bg0, BsW);
        ldg_lds16(Bg1, BsW + 2048);
        __syncthreads();
        short8 a[4], b[4];
#pragma unroll
        for (int mt = 0; mt < 4; ++mt)
            a[mt] = *(const short8*)(As + (size_t)(wr * 64 + mt * 16 + mrow) * 32 + koff);
#pragma unroll
        for (int nt = 0; nt < 4; ++nt)
            b[nt] = *(const short8*)(Bs + (size_t)(wc * 64 + nt * 16 + mrow) * 32 + koff);
#pragma unroll
        for (int mt = 0; mt < 4; ++mt)
#pragma unroll
            for (int nt = 0; nt < 4; ++nt)
                acc[mt][nt] = __builtin_amdgcn_mfma_f32_16x16x32_bf16(
                    a[mt], b[nt], acc[mt][nt], 0, 0, 0);
        __syncthreads();
        Ag0 += 32; Ag1 += 32; Bg0 += 32; Bg1 += 32;
    }

    // epilogue: stage C tile in LDS, coalesced dwordx4 stores
#pragma unroll
    for (int mt = 0; mt < 4; ++mt) {
        int rl = wr * 64 + mt * 16 + (lane >> 4) * 4;
#pragma unroll
        for (int nt = 0; nt < 4; ++nt) {
            int cl = wc * 64 + nt * 16 + (lane & 15);
            float bv = bias[col0 + cl];
#pragma unroll
            for (int q = 0; q < 4; ++q) {
                float v = actf(acc[mt][nt][q] + bv, act);
                smem[(size_t)(rl + q) * CPITCH + cl] = f2b(v);
            }
        }
    }
    __syncthreads();
    int rr = t >> 4;
    int seg = t & 15;
#pragma unroll
    for (int pass = 0; pass < 8; ++pass) {
        int row = pass * 16 + rr;
        uint4 val = *(const uint4*)(smem + (size_t)row * CPITCH + seg * 8);
        *(uint4*)(C + (size_t)(row0 + row) * ldc + col0 + seg * 8) = val;
    }
}

// ---------- pooling (merged): graph g in [0,4096) -> z[g&2047, (g>>11)*256+] ----------
__global__ __launch_bounds__(256) void pool_kernel(const u16* __restrict__ h,
                                                   u16* __restrict__ z) {
    int g = blockIdx.x, f = threadIdx.x;
    float acc = 0.f;
    const u16* base = h + (size_t)g * 40 * H + f;
#pragma unroll
    for (int j = 0; j < 40; ++j) acc += b2f(base[j * H]);
    int zrow = g & (NB - 1);
    int zoff = (g >> 11) * H;
    z[(size_t)zrow * ZK + zoff + f] = f2b(acc);
}

__global__ void copy_add_kernel(const float* __restrict__ add, u16* __restrict__ z) {
    int i = blockIdx.x * 256 + threadIdx.x;
    if (i < NB * 8) {
        int g = i >> 3, a = i & 7;
        z[(size_t)g * ZK + 512 + a] = f2b(add[i]);
    }
}

// ---------- final GEMV: out[r] = sum_k m2b[r,k]*w[k] + b ----------
__global__ void gemv_out_kernel(const u16* __restrict__ A, const float* __restrict__ w,
                                const float* __restrict__ b, float* __restrict__ out, int K) {
    int wave = threadIdx.x >> 6;
    int lane = threadIdx.x & 63;
    int row = blockIdx.x * 4 + wave;
    float acc = 0.f;
    for (int k = lane; k < K; k += 64) acc += b2f(A[(size_t)row * K + k]) * w[k];
#pragma unroll
    for (int off = 32; off > 0; off >>= 1) acc += __shfl_down(acc, off, 64);
    if (lane == 0) out[row] = acc + b[0];
}

extern "C" void kernel_launch(void* const* d_in, const int* in_sizes, int n_in,
                              void* d_out, int out_size, void* d_ws, size_t ws_size,
                              hipStream_t stream) {
    const int*   cat_src = (const int*)d_in[0];
    const int*   cat_dst = (const int*)d_in[1];
    const float* cat_x   = (const float*)d_in[3];
    const int*   an_src  = (const int*)d_in[4];
    const int*   an_dst  = (const int*)d_in[5];
    const float* an_x    = (const float*)d_in[7];
    const float* add_f   = (const float*)d_in[8];
    const float* W0      = (const float*)d_in[9];
    const float* b0      = (const float*)d_in[10];
    const float* gcrW    = (const float*)d_in[11];
    const float* gcrb    = (const float*)d_in[12];
    const float* mW1     = (const float*)d_in[13];
    const float* mb1     = (const float*)d_in[14];
    const float* mW2     = (const float*)d_in[15];
    const float* mb2     = (const float*)d_in[16];
    const float* mW3     = (const float*)d_in[17];
    const float* mb3     = (const float*)d_in[18];
    float* out = (float*)d_out;

    // ---- workspace carve (~205 MB; xb/aggx alias hA/hB dead ranges) ----
    char* p = (char*)d_ws;
    auto alloc = [&](size_t bytes) -> void* {
        void* rp = (void*)p;
        p += (bytes + 255) & ~(size_t)255;
        return rp;
    };
    int*   dego   = (int*)alloc((size_t)NN2 * 4);
    int*   cnti   = (int*)alloc((size_t)NN2 * 4);
    int*   bucket = (int*)alloc((size_t)NN2 * DEGCAP * 4);
    float* rso    = (float*)alloc((size_t)NN2 * 4);
    float* rsi    = (float*)alloc((size_t)NN2 * 4);
    u16*   hA     = (u16*)alloc((size_t)NN2 * H * 2);   // 84 MB
    u16*   hB     = (u16*)alloc((size_t)NN2 * H * 2);   // 84 MB
    u16*   Wt0    = (u16*)alloc((size_t)H * KPAD * 2);
    u16*   Wtg    = (u16*)alloc((size_t)10 * H * H * 2);
    u16*   Wt1    = (u16*)alloc((size_t)1024 * ZK * 2);
    u16*   Wt2    = (u16*)alloc((size_t)512 * 1024 * 2);
    u16*   zb     = (u16*)alloc((size_t)NB * ZK * 2);
    u16*   m1b    = (u16*)alloc((size_t)NB * 1024 * 2);
    u16*   m2b    = (u16*)alloc((size_t)NB * 512 * 2);
    u16*   xb     = hA;   // NN2*INDIM*2 = 24 MB, dead after gather_x
    u16*   aggx   = hB;   // NN2*KPAD*2 = 42 MB, dead after first GEMM
    (void)ws_size; (void)in_sizes; (void)n_in; (void)out_size;

    // weight prep (bf16 transposed)
    prep_w0_kernel<<<(H * KPAD) / 256, 256, 0, stream>>>(W0, Wt0);
    prep_gcr_kernel<<<dim3(H * H / 256, 10), 256, 0, stream>>>(gcrW, Wtg);
    prep_w1_kernel<<<(1024 * ZK + 255) / 256, 256, 0, stream>>>(mW1, Wt1);
    prep_w2_kernel<<<(512 * 1024) / 256, 256, 0, stream>>>(mW2, Wt2);
    hipMemsetAsync(zb, 0, (size_t)NB * ZK * 2, stream);  // zero K-pad cols
    hipMemsetAsync(dego, 0, (size_t)NN2 * 4, stream);
    hipMemsetAsync(cnti, 0, (size_t)NN2 * 4, stream);

    // merged graph prep
    fill_kernel<<<NE2 / 256, 256, 0, stream>>>(cat_src, cat_dst, an_src, an_dst,
                                               dego, cnti, bucket);
    rsqrt_kernel<<<NN2 / 256, 256, 0, stream>>>(dego, cnti, rso, rsi);

    // first conv (merged): prescale -> gather -> GEMM K=128
    prescale_x_kernel<<<NN2, 128, 0, stream>>>(cat_x, an_x, rso, xb);
    gather_x_kernel<<<NN2, 128, 0, stream>>>(xb, bucket, cnti, rsi, aggx);
    gemm_mfma_kernel<<<dim3(NN2 / 128, H / 128), 256, 0, stream>>>(
        aggx, KPAD, Wt0, KPAD, b0, hA, H, KPAD / 32, 0);

    // 10 conv layers (merged): gather hA->hB, GEMM hB->hA
    for (int l = 0; l < 10; ++l) {
        gather_h_kernel<<<NN2 / 8, 256, 0, stream>>>(hA, bucket, cnti, rso, rsi, hB);
        gemm_mfma_kernel<<<dim3(NN2 / 128, H / 128), 256, 0, stream>>>(
            hB, H, Wtg + (size_t)l * H * H, H, gcrb + (size_t)l * H, hA, H,
            H / 32, 1);
    }
    pool_kernel<<<NB2, 256, 0, stream>>>(hA, zb);
    copy_add_kernel<<<(NB * 8 + 255) / 256, 256, 0, stream>>>(add_f, zb);

    // MLP head (bf16 MFMA)
    gemm_mfma_kernel<<<dim3(NB / 128, 1024 / 128), 256, 0, stream>>>(
        zb, ZK, Wt1, ZK, mb1, m1b, 1024, ZK / 32, 2);
    gemm_mfma_kernel<<<dim3(NB / 128, 512 / 128), 256, 0, stream>>>(
        m1b, 1024, Wt2, 1024, mb2, m2b, 512, 1024 / 32, 2);
    gemv_out_kernel<<<NB / 4, 256, 0, stream>>>(m2b, mW3, mb3, out, 512);
}

// Round 9
// 1527.802 us; speedup vs baseline: 1.9742x; 1.0501x over previous
//
#include <hip/hip_runtime.h>

// SolvGNNV6 round 9: merged pipeline (r8) + aligned-row gather_x (KPAD rows,
// uint4/16-lane like gather_h), GEMM grid swizzle (col fastest -> A re-read
// L2-hot), int4 bucket loads.

#define NN 81920     // nodes per side
#define NN2 163840   // merged nodes (cat | an+NN)
#define NE 327680    // edges per side
#define NE2 655360
#define NB 2048      // graphs per side
#define NB2 4096
#define H 256
#define INDIM 74
#define KPAD 128     // first-conv K padded 74 -> 128
#define ZK 544       // MLP1 K padded 520 -> 544 (17 * 32)
#define DEGCAP 32    // max in-degree bucket (Poisson(4); P(>32) ~ 1e-19)
#define CPITCH 132   // C-tile LDS pitch (u16) for gemm epilogue

typedef unsigned short u16;
typedef __attribute__((ext_vector_type(8))) short short8;  // 8 bf16 (4 VGPRs)
typedef __attribute__((ext_vector_type(4))) float f32x4;

__device__ inline u16 f2b(float f) {  // fp32 -> bf16 bits, RNE
    unsigned u = __builtin_bit_cast(unsigned, f);
    u += 0x7fffu + ((u >> 16) & 1u);
    return (u16)(u >> 16);
}
__device__ inline float b2f(u16 b) {
    unsigned u = ((unsigned)b) << 16;
    return __builtin_bit_cast(float, u);
}
__device__ inline float blo(unsigned u) { return __builtin_bit_cast(float, u << 16); }
__device__ inline float bhi(unsigned u) { return __builtin_bit_cast(float, u & 0xffff0000u); }

// ---------- merged degree count + bucket fill ----------
__global__ void fill_kernel(const int* __restrict__ cs, const int* __restrict__ cd,
                            const int* __restrict__ as_, const int* __restrict__ ad,
                            int* __restrict__ dego, int* __restrict__ cnti,
                            int* __restrict__ bucket) {
    int e = blockIdx.x * 256 + threadIdx.x;
    if (e < NE2) {
        int s, d;
        if (e < NE) { s = cs[e]; d = cd[e]; }
        else        { s = as_[e - NE] + NN; d = ad[e - NE] + NN; }
        atomicAdd(&dego[s], 1);
        int p = atomicAdd(&cnti[d], 1);
        if (p < DEGCAP) bucket[d * DEGCAP + p] = s;
    }
}

__global__ void rsqrt_kernel(const int* __restrict__ dego, const int* __restrict__ cnti,
                             float* __restrict__ rso, float* __restrict__ rsi) {
    int i = blockIdx.x * 256 + threadIdx.x;
    if (i < NN2) {
        rso[i] = rsqrtf((float)(dego[i] > 1 ? dego[i] : 1));
        rsi[i] = rsqrtf((float)(cnti[i] > 1 ? cnti[i] : 1));
    }
}

// ---------- prescale x by rso -> bf16, pad rows to 128 cols (256 B aligned) ----------
__global__ __launch_bounds__(256) void prescale_x_kernel(
        const float* __restrict__ cx, const float* __restrict__ ax,
        const float* __restrict__ rso, u16* __restrict__ xbp) {
    int t = threadIdx.x;
    int node = blockIdx.x * 4 + (t >> 6);
    int lane = t & 63;                    // 64 u32 = 128 u16 per row
    const float* x = (node < NN) ? (cx + (size_t)node * INDIM)
                                 : (ax + (size_t)(node - NN) * INDIM);
    float w = rso[node];
    int f0 = lane * 2, f1 = f0 + 1;
    u16 a = (f0 < INDIM) ? f2b(x[f0] * w) : (u16)0;
    u16 b = (f1 < INDIM) ? f2b(x[f1] * w) : (u16)0;
    ((unsigned*)xbp)[(size_t)node * 64 + lane] = a | ((unsigned)b << 16);
}

// ---------- first-conv aggregation: 16 lanes/node, uint4 rows (KPAD layout) ----------
__global__ __launch_bounds__(256) void gather_x_kernel(
        const u16* __restrict__ xbp, const int* __restrict__ bucket,
        const int* __restrict__ cnti, const float* __restrict__ rsi,
        u16* __restrict__ out) {
    int node = blockIdx.x * 16 + (threadIdx.x >> 4);
    int fc = (threadIdx.x & 15) * 8;      // 8 bf16 = 16 B per thread
    int deg = cnti[node]; if (deg > DEGCAP) deg = DEGCAP;
    const int* bk = bucket + node * DEGCAP;
    float acc[8] = {};
    for (int base = 0; base < deg; base += 4) {
        int4 b4 = *(const int4*)(bk + base);   // one lane-uniform 16 B load
        int i0 = b4.x;
        int i1 = (base + 1 < deg) ? b4.y : i0;
        int i2 = (base + 2 < deg) ? b4.z : i0;
        int i3 = (base + 3 < deg) ? b4.w : i0;
        float m1 = (base + 1 < deg) ? 1.f : 0.f;
        float m2 = (base + 2 < deg) ? 1.f : 0.f;
        float m3 = (base + 3 < deg) ? 1.f : 0.f;
        uint4 v0 = *(const uint4*)(xbp + (size_t)i0 * KPAD + fc);
        uint4 v1 = *(const uint4*)(xbp + (size_t)i1 * KPAD + fc);
        uint4 v2 = *(const uint4*)(xbp + (size_t)i2 * KPAD + fc);
        uint4 v3 = *(const uint4*)(xbp + (size_t)i3 * KPAD + fc);
        acc[0] += blo(v0.x) + m1 * blo(v1.x) + m2 * blo(v2.x) + m3 * blo(v3.x);
        acc[1] += bhi(v0.x) + m1 * bhi(v1.x) + m2 * bhi(v2.x) + m3 * bhi(v3.x);
        acc[2] += blo(v0.y) + m1 * blo(v1.y) + m2 * blo(v2.y) + m3 * blo(v3.y);
        acc[3] += bhi(v0.y) + m1 * bhi(v1.y) + m2 * bhi(v2.y) + m3 * bhi(v3.y);
        acc[4] += blo(v0.z) + m1 * blo(v1.z) + m2 * blo(v2.z) + m3 * blo(v3.z);
        acc[5] += bhi(v0.z) + m1 * bhi(v1.z) + m2 * bhi(v2.z) + m3 * bhi(v3.z);
        acc[6] += blo(v0.w) + m1 * blo(v1.w) + m2 * blo(v2.w) + m3 * blo(v3.w);
        acc[7] += bhi(v0.w) + m1 * bhi(v1.w) + m2 * bhi(v2.w) + m3 * bhi(v3.w);
    }
    float ri = rsi[node];
    u16 o[8];
#pragma unroll
    for (int i = 0; i < 8; ++i) o[i] = f2b(acc[i] * ri);
    uint4 ov;
    ov.x = o[0] | ((unsigned)o[1] << 16);
    ov.y = o[2] | ((unsigned)o[3] << 16);
    ov.z = o[4] | ((unsigned)o[5] << 16);
    ov.w = o[6] | ((unsigned)o[7] << 16);
    *(uint4*)(out + (size_t)node * KPAD + fc) = ov;
}

// ---------- H-dim aggregation, 4-wide neighbor batching ----------
__global__ __launch_bounds__(256) void gather_h_kernel(
        const u16* __restrict__ h, const int* __restrict__ bucket,
        const int* __restrict__ cnti, const float* __restrict__ rso,
        const float* __restrict__ rsi, u16* __restrict__ out) {
    int node = blockIdx.x * 8 + (threadIdx.x >> 5);
    int fc = (threadIdx.x & 31) * 8;     // 8 bf16 = 16 B per thread
    int deg = cnti[node]; if (deg > DEGCAP) deg = DEGCAP;
    const int* bk = bucket + node * DEGCAP;
    float acc[8] = {};
    for (int base = 0; base < deg; base += 4) {
        int4 b4 = *(const int4*)(bk + base);
        int i0 = b4.x;
        int i1 = (base + 1 < deg) ? b4.y : i0;
        int i2 = (base + 2 < deg) ? b4.z : i0;
        int i3 = (base + 3 < deg) ? b4.w : i0;
        float w0 = rso[i0];
        float w1 = (base + 1 < deg) ? rso[i1] : 0.f;
        float w2 = (base + 2 < deg) ? rso[i2] : 0.f;
        float w3 = (base + 3 < deg) ? rso[i3] : 0.f;
        uint4 v0 = *(const uint4*)(h + (size_t)i0 * H + fc);
        uint4 v1 = *(const uint4*)(h + (size_t)i1 * H + fc);
        uint4 v2 = *(const uint4*)(h + (size_t)i2 * H + fc);
        uint4 v3 = *(const uint4*)(h + (size_t)i3 * H + fc);
        acc[0] += blo(v0.x) * w0 + blo(v1.x) * w1 + blo(v2.x) * w2 + blo(v3.x) * w3;
        acc[1] += bhi(v0.x) * w0 + bhi(v1.x) * w1 + bhi(v2.x) * w2 + bhi(v3.x) * w3;
        acc[2] += blo(v0.y) * w0 + blo(v1.y) * w1 + blo(v2.y) * w2 + blo(v3.y) * w3;
        acc[3] += bhi(v0.y) * w0 + bhi(v1.y) * w1 + bhi(v2.y) * w2 + bhi(v3.y) * w3;
        acc[4] += blo(v0.z) * w0 + blo(v1.z) * w1 + blo(v2.z) * w2 + blo(v3.z) * w3;
        acc[5] += bhi(v0.z) * w0 + bhi(v1.z) * w1 + bhi(v2.z) * w2 + bhi(v3.z) * w3;
        acc[6] += blo(v0.w) * w0 + blo(v1.w) * w1 + blo(v2.w) * w2 + blo(v3.w) * w3;
        acc[7] += bhi(v0.w) * w0 + bhi(v1.w) * w1 + bhi(v2.w) * w2 + bhi(v3.w) * w3;
    }
    float ri = rsi[node];
    u16 o[8];
#pragma unroll
    for (int i = 0; i < 8; ++i) o[i] = f2b(acc[i] * ri);
    uint4 ov;
    ov.x = o[0] | ((unsigned)o[1] << 16);
    ov.y = o[2] | ((unsigned)o[3] << 16);
    ov.z = o[4] | ((unsigned)o[5] << 16);
    ov.w = o[6] | ((unsigned)o[7] << 16);
    *(uint4*)(out + (size_t)node * H + fc) = ov;
}

// ---------- weight prep: fp32 row-major -> bf16 transposed ----------
__global__ void prep_w0_kernel(const float* __restrict__ W0, u16* __restrict__ Wt0) {
    int i = blockIdx.x * 256 + threadIdx.x;  // 256*128
    int n = i >> 7, k = i & 127;
    float v = (k < INDIM) ? W0[(size_t)k * H + n] : 0.f;
    Wt0[i] = f2b(v);
}

__global__ void prep_gcr_kernel(const float* __restrict__ W, u16* __restrict__ Wt) {
    int i = blockIdx.x * 256 + threadIdx.x;  // 65536 per layer
    int l = blockIdx.y;                      // 0..9
    int n = i >> 8, k = i & 255;
    Wt[(size_t)l * 65536 + i] = f2b(W[(size_t)l * 65536 + (size_t)k * H + n]);
}

__global__ void prep_w1_kernel(const float* __restrict__ W, u16* __restrict__ Wt) {
    int i = blockIdx.x * 256 + threadIdx.x;  // 1024 * 544
    if (i >= 1024 * ZK) return;
    int n = i / ZK, k = i - n * ZK;
    float v = (k < 520) ? W[(size_t)k * 1024 + n] : 0.f;
    Wt[i] = f2b(v);
}

__global__ void prep_w2_kernel(const float* __restrict__ W, u16* __restrict__ Wt) {
    int i = blockIdx.x * 256 + threadIdx.x;  // 512 * 1024
    int n = i >> 10, k = i & 1023;
    Wt[i] = f2b(W[(size_t)k * 512 + n]);
}

// ---------- bf16 MFMA GEMM helpers ----------
__device__ inline void ldg_lds16(const u16* g, u16* l) {
    __builtin_amdgcn_global_load_lds(
        (const __attribute__((address_space(1))) unsigned int*)g,
        (__attribute__((address_space(3))) unsigned int*)l, 16, 0, 0);
}
__device__ inline float actf(float v, int act) {
    if (act == 1) return fmaxf(v, 0.f);
    if (act == 2) return (v > 0.f) ? v : 0.01f * v;
    return v;
}

// ---------- 128x128 MFMA GEMM: C = act(A @ Bt^T + bias), BK=32 ----------
// grid (N/128, M/128): col index FASTEST so both col-blocks of a row-block
// dispatch adjacently -> A-tile re-read is L2/L3-hot.
__global__ __launch_bounds__(256) void gemm_mfma_kernel(
        const u16* __restrict__ A, int lda,
        const u16* __restrict__ Bt, int ldb,
        const float* __restrict__ bias, u16* __restrict__ C, int ldc,
        int Kiters, int act) {
    __shared__ __align__(16) u16 smem[128 * CPITCH];  // 33 KB; overlays As/Bs
    u16* As = smem;
    u16* Bs = smem + 4096;
    int t = threadIdx.x;
    int wave = t >> 6, lane = t & 63;
    int wr = wave >> 1, wc = wave & 1;
    int row0 = blockIdx.y * 128, col0 = blockIdx.x * 128;

    int r = t >> 2;
    int kq = (t & 3) * 8;
    const u16* Ag0 = A + (size_t)(row0 + r) * lda + kq;
    const u16* Ag1 = A + (size_t)(row0 + 64 + r) * lda + kq;
    const u16* Bg0 = Bt + (size_t)(col0 + r) * ldb + kq;
    const u16* Bg1 = Bt + (size_t)(col0 + 64 + r) * ldb + kq;
    u16* AsW = As + wave * 512;
    u16* BsW = Bs + wave * 512;

    f32x4 acc[4][4] = {};
    int mrow = lane & 15;
    int koff = (lane >> 4) * 8;

    for (int kt = 0; kt < Kiters; ++kt) {
        ldg_lds16(Ag0, AsW);
        ldg_lds16(Ag1, AsW + 2048);
        ldg_lds16(Bg0, BsW);
        ldg_lds16(Bg1, BsW + 2048);
        __syncthreads();
        short8 a[4], b[4];
#pragma unroll
        for (int mt = 0; mt < 4; ++mt)
            a[mt] = *(const short8*)(As + (size_t)(wr * 64 + mt * 16 + mrow) * 32 + koff);
#pragma unroll
        for (int nt = 0; nt < 4; ++nt)
            b[nt] = *(const short8*)(Bs + (size_t)(wc * 64 + nt * 16 + mrow) * 32 + koff);
#pragma unroll
        for (int mt = 0; mt < 4; ++mt)
#pragma unroll
            for (int nt = 0; nt < 4; ++nt)
                acc[mt][nt] = __builtin_amdgcn_mfma_f32_16x16x32_bf16(
                    a[mt], b[nt], acc[mt][nt], 0, 0, 0);
        __syncthreads();
        Ag0 += 32; Ag1 += 32; Bg0 += 32; Bg1 += 32;
    }

    // epilogue: stage C tile in LDS, coalesced dwordx4 stores
#pragma unroll
    for (int mt = 0; mt < 4; ++mt) {
        int rl = wr * 64 + mt * 16 + (lane >> 4) * 4;
#pragma unroll
        for (int nt = 0; nt < 4; ++nt) {
            int cl = wc * 64 + nt * 16 + (lane & 15);
            float bv = bias[col0 + cl];
#pragma unroll
            for (int q = 0; q < 4; ++q) {
                float v = actf(acc[mt][nt][q] + bv, act);
                smem[(size_t)(rl + q) * CPITCH + cl] = f2b(v);
            }
        }
    }
    __syncthreads();
    int rr = t >> 4;
    int seg = t & 15;
#pragma unroll
    for (int pass = 0; pass < 8; ++pass) {
        int row = pass * 16 + rr;
        uint4 val = *(const uint4*)(smem + (size_t)row * CPITCH + seg * 8);
        *(uint4*)(C + (size_t)(row0 + row) * ldc + col0 + seg * 8) = val;
    }
}

// ---------- pooling (merged): graph g in [0,4096) -> z[g&2047, (g>>11)*256+] ----------
__global__ __launch_bounds__(256) void pool_kernel(const u16* __restrict__ h,
                                                   u16* __restrict__ z) {
    int g = blockIdx.x, f = threadIdx.x;
    float acc = 0.f;
    const u16* base = h + (size_t)g * 40 * H + f;
#pragma unroll
    for (int j = 0; j < 40; ++j) acc += b2f(base[j * H]);
    int zrow = g & (NB - 1);
    int zoff = (g >> 11) * H;
    z[(size_t)zrow * ZK + zoff + f] = f2b(acc);
}

__global__ void copy_add_kernel(const float* __restrict__ add, u16* __restrict__ z) {
    int i = blockIdx.x * 256 + threadIdx.x;
    if (i < NB * 8) {
        int g = i >> 3, a = i & 7;
        z[(size_t)g * ZK + 512 + a] = f2b(add[i]);
    }
}

// ---------- final GEMV: out[r] = sum_k m2b[r,k]*w[k] + b ----------
__global__ void gemv_out_kernel(const u16* __restrict__ A, const float* __restrict__ w,
                                const float* __restrict__ b, float* __restrict__ out, int K) {
    int wave = threadIdx.x >> 6;
    int lane = threadIdx.x & 63;
    int row = blockIdx.x * 4 + wave;
    float acc = 0.f;
    for (int k = lane; k < K; k += 64) acc += b2f(A[(size_t)row * K + k]) * w[k];
#pragma unroll
    for (int off = 32; off > 0; off >>= 1) acc += __shfl_down(acc, off, 64);
    if (lane == 0) out[row] = acc + b[0];
}

extern "C" void kernel_launch(void* const* d_in, const int* in_sizes, int n_in,
                              void* d_out, int out_size, void* d_ws, size_t ws_size,
                              hipStream_t stream) {
    const int*   cat_src = (const int*)d_in[0];
    const int*   cat_dst = (const int*)d_in[1];
    const float* cat_x   = (const float*)d_in[3];
    const int*   an_src  = (const int*)d_in[4];
    const int*   an_dst  = (const int*)d_in[5];
    const float* an_x    = (const float*)d_in[7];
    const float* add_f   = (const float*)d_in[8];
    const float* W0      = (const float*)d_in[9];
    const float* b0      = (const float*)d_in[10];
    const float* gcrW    = (const float*)d_in[11];
    const float* gcrb    = (const float*)d_in[12];
    const float* mW1     = (const float*)d_in[13];
    const float* mb1     = (const float*)d_in[14];
    const float* mW2     = (const float*)d_in[15];
    const float* mb2     = (const float*)d_in[16];
    const float* mW3     = (const float*)d_in[17];
    const float* mb3     = (const float*)d_in[18];
    float* out = (float*)d_out;

    // ---- workspace carve (~205 MB; xbp/aggx alias hA/hB dead ranges) ----
    char* p = (char*)d_ws;
    auto alloc = [&](size_t bytes) -> void* {
        void* rp = (void*)p;
        p += (bytes + 255) & ~(size_t)255;
        return rp;
    };
    int*   dego   = (int*)alloc((size_t)NN2 * 4);
    int*   cnti   = (int*)alloc((size_t)NN2 * 4);
    int*   bucket = (int*)alloc((size_t)NN2 * DEGCAP * 4);
    float* rso    = (float*)alloc((size_t)NN2 * 4);
    float* rsi    = (float*)alloc((size_t)NN2 * 4);
    u16*   hA     = (u16*)alloc((size_t)NN2 * H * 2);   // 84 MB
    u16*   hB     = (u16*)alloc((size_t)NN2 * H * 2);   // 84 MB
    u16*   Wt0    = (u16*)alloc((size_t)H * KPAD * 2);
    u16*   Wtg    = (u16*)alloc((size_t)10 * H * H * 2);
    u16*   Wt1    = (u16*)alloc((size_t)1024 * ZK * 2);
    u16*   Wt2    = (u16*)alloc((size_t)512 * 1024 * 2);
    u16*   zb     = (u16*)alloc((size_t)NB * ZK * 2);
    u16*   m1b    = (u16*)alloc((size_t)NB * 1024 * 2);
    u16*   m2b    = (u16*)alloc((size_t)NB * 512 * 2);
    u16*   xbp    = hA;   // NN2*KPAD*2 = 42 MB, dead after gather_x
    u16*   aggx   = hB;   // NN2*KPAD*2 = 42 MB, dead after first GEMM
    (void)ws_size; (void)in_sizes; (void)n_in; (void)out_size;

    // weight prep (bf16 transposed)
    prep_w0_kernel<<<(H * KPAD) / 256, 256, 0, stream>>>(W0, Wt0);
    prep_gcr_kernel<<<dim3(H * H / 256, 10), 256, 0, stream>>>(gcrW, Wtg);
    prep_w1_kernel<<<(1024 * ZK + 255) / 256, 256, 0, stream>>>(mW1, Wt1);
    prep_w2_kernel<<<(512 * 1024) / 256, 256, 0, stream>>>(mW2, Wt2);
    hipMemsetAsync(zb, 0, (size_t)NB * ZK * 2, stream);  // zero K-pad cols
    hipMemsetAsync(dego, 0, (size_t)NN2 * 4, stream);
    hipMemsetAsync(cnti, 0, (size_t)NN2 * 4, stream);

    // merged graph prep
    fill_kernel<<<NE2 / 256, 256, 0, stream>>>(cat_src, cat_dst, an_src, an_dst,
                                               dego, cnti, bucket);
    rsqrt_kernel<<<NN2 / 256, 256, 0, stream>>>(dego, cnti, rso, rsi);

    // first conv (merged): prescale (padded rows) -> gather -> GEMM K=128
    prescale_x_kernel<<<NN2 / 4, 256, 0, stream>>>(cat_x, an_x, rso, xbp);
    gather_x_kernel<<<NN2 / 16, 256, 0, stream>>>(xbp, bucket, cnti, rsi, aggx);
    gemm_mfma_kernel<<<dim3(H / 128, NN2 / 128), 256, 0, stream>>>(
        aggx, KPAD, Wt0, KPAD, b0, hA, H, KPAD / 32, 0);

    // 10 conv layers (merged): gather hA->hB, GEMM hB->hA
    for (int l = 0; l < 10; ++l) {
        gather_h_kernel<<<NN2 / 8, 256, 0, stream>>>(hA, bucket, cnti, rso, rsi, hB);
        gemm_mfma_kernel<<<dim3(H / 128, NN2 / 128), 256, 0, stream>>>(
            hB, H, Wtg + (size_t)l * H * H, H, gcrb + (size_t)l * H, hA, H,
            H / 32, 1);
    }
    pool_kernel<<<NB2, 256, 0, stream>>>(hA, zb);
    copy_add_kernel<<<(NB * 8 + 255) / 256, 256, 0, stream>>>(add_f, zb);

    // MLP head (bf16 MFMA)
    gemm_mfma_kernel<<<dim3(1024 / 128, NB / 128), 256, 0, stream>>>(
        zb, ZK, Wt1, ZK, mb1, m1b, 1024, ZK / 32, 2);
    gemm_mfma_kernel<<<dim3(512 / 128, NB / 128), 256, 0, stream>>>(
        m1b, 1024, Wt2, 1024, mb2, m2b, 512, 1024 / 32, 2);
    gemv_out_kernel<<<NB / 4, 256, 0, stream>>>(m2b, mW3, mb3, out, 512);
}

// Round 10
// 1488.636 us; speedup vs baseline: 2.0261x; 1.0263x over previous
//
#include <hip/hip_runtime.h>

// SolvGNNV6 round 10: transposed bucket (p*NN2+d -> write-allocate fix, fill
// was 58 MB WRITE for 2.6 MB of data) + BK=64 GEMM with XOR-swizzled staging
// (half the barriers, bank-clean). Merged pipeline from r8/r9.

#define NN 81920     // nodes per side
#define NN2 163840   // merged nodes (cat | an+NN)
#define NE 327680    // edges per side
#define NE2 655360
#define NB 2048      // graphs per side
#define NB2 4096
#define H 256
#define INDIM 74
#define KPAD 128     // first-conv K padded 74 -> 128
#define ZK 576       // MLP1 K padded 520 -> 576 (9 * 64)
#define DEGCAP 32    // max in-degree bucket (Poisson(4); P(>32) ~ 1e-19)
#define CPITCH 132   // C-tile LDS pitch (u16) for gemm epilogue

typedef unsigned short u16;
typedef __attribute__((ext_vector_type(8))) short short8;  // 8 bf16 (4 VGPRs)
typedef __attribute__((ext_vector_type(4))) float f32x4;

__device__ inline u16 f2b(float f) {  // fp32 -> bf16 bits, RNE
    unsigned u = __builtin_bit_cast(unsigned, f);
    u += 0x7fffu + ((u >> 16) & 1u);
    return (u16)(u >> 16);
}
__device__ inline float b2f(u16 b) {
    unsigned u = ((unsigned)b) << 16;
    return __builtin_bit_cast(float, u);
}
__device__ inline float blo(unsigned u) { return __builtin_bit_cast(float, u << 16); }
__device__ inline float bhi(unsigned u) { return __builtin_bit_cast(float, u & 0xffff0000u); }

// ---------- merged degree count + TRANSPOSED bucket fill ----------
// bucket[p*NN2 + d]: slot-p writes land dense in a 655 KB region -> lines
// fully populated -> no write-allocate blowup (was 58 MB WRITE for 2.6 MB).
__global__ void fill_kernel(const int* __restrict__ cs, const int* __restrict__ cd,
                            const int* __restrict__ as_, const int* __restrict__ ad,
                            int* __restrict__ dego, int* __restrict__ cnti,
                            int* __restrict__ bucket) {
    int e = blockIdx.x * 256 + threadIdx.x;
    if (e < NE2) {
        int s, d;
        if (e < NE) { s = cs[e]; d = cd[e]; }
        else        { s = as_[e - NE] + NN; d = ad[e - NE] + NN; }
        atomicAdd(&dego[s], 1);
        int p = atomicAdd(&cnti[d], 1);
        if (p < DEGCAP) bucket[(size_t)p * NN2 + d] = s;
    }
}

__global__ void rsqrt_kernel(const int* __restrict__ dego, const int* __restrict__ cnti,
                             float* __restrict__ rso, float* __restrict__ rsi) {
    int i = blockIdx.x * 256 + threadIdx.x;
    if (i < NN2) {
        rso[i] = rsqrtf((float)(dego[i] > 1 ? dego[i] : 1));
        rsi[i] = rsqrtf((float)(cnti[i] > 1 ? cnti[i] : 1));
    }
}

// ---------- prescale x by rso -> bf16, pad rows to 128 cols (256 B aligned) ----------
__global__ __launch_bounds__(256) void prescale_x_kernel(
        const float* __restrict__ cx, const float* __restrict__ ax,
        const float* __restrict__ rso, u16* __restrict__ xbp) {
    int t = threadIdx.x;
    int node = blockIdx.x * 4 + (t >> 6);
    int lane = t & 63;                    // 64 u32 = 128 u16 per row
    const float* x = (node < NN) ? (cx + (size_t)node * INDIM)
                                 : (ax + (size_t)(node - NN) * INDIM);
    float w = rso[node];
    int f0 = lane * 2, f1 = f0 + 1;
    u16 a = (f0 < INDIM) ? f2b(x[f0] * w) : (u16)0;
    u16 b = (f1 < INDIM) ? f2b(x[f1] * w) : (u16)0;
    ((unsigned*)xbp)[(size_t)node * 64 + lane] = a | ((unsigned)b << 16);
}

// ---------- first-conv aggregation: 16 lanes/node, transposed-bucket reads ----------
__global__ __launch_bounds__(256) void gather_x_kernel(
        const u16* __restrict__ xbp, const int* __restrict__ bucket,
        const int* __restrict__ cnti, const float* __restrict__ rsi,
        u16* __restrict__ out) {
    int node = blockIdx.x * 16 + (threadIdx.x >> 4);
    int fc = (threadIdx.x & 15) * 8;      // 8 bf16 = 16 B per thread
    int deg = cnti[node]; if (deg > DEGCAP) deg = DEGCAP;
    const int* bk = bucket + node;        // stride NN2 per slot
    float acc[8] = {};
    for (int base = 0; base < deg; base += 4) {
        // adjacent nodes read adjacent ints -> one line serves 16 nodes
        int i0 = bk[(size_t)base * NN2];
        int i1 = (base + 1 < deg) ? bk[(size_t)(base + 1) * NN2] : i0;
        int i2 = (base + 2 < deg) ? bk[(size_t)(base + 2) * NN2] : i0;
        int i3 = (base + 3 < deg) ? bk[(size_t)(base + 3) * NN2] : i0;
        float m1 = (base + 1 < deg) ? 1.f : 0.f;
        float m2 = (base + 2 < deg) ? 1.f : 0.f;
        float m3 = (base + 3 < deg) ? 1.f : 0.f;
        uint4 v0 = *(const uint4*)(xbp + (size_t)i0 * KPAD + fc);
        uint4 v1 = *(const uint4*)(xbp + (size_t)i1 * KPAD + fc);
        uint4 v2 = *(const uint4*)(xbp + (size_t)i2 * KPAD + fc);
        uint4 v3 = *(const uint4*)(xbp + (size_t)i3 * KPAD + fc);
        acc[0] += blo(v0.x) + m1 * blo(v1.x) + m2 * blo(v2.x) + m3 * blo(v3.x);
        acc[1] += bhi(v0.x) + m1 * bhi(v1.x) + m2 * bhi(v2.x) + m3 * bhi(v3.x);
        acc[2] += blo(v0.y) + m1 * blo(v1.y) + m2 * blo(v2.y) + m3 * blo(v3.y);
        acc[3] += bhi(v0.y) + m1 * bhi(v1.y) + m2 * bhi(v2.y) + m3 * bhi(v3.y);
        acc[4] += blo(v0.z) + m1 * blo(v1.z) + m2 * blo(v2.z) + m3 * blo(v3.z);
        acc[5] += bhi(v0.z) + m1 * bhi(v1.z) + m2 * bhi(v2.z) + m3 * bhi(v3.z);
        acc[6] += blo(v0.w) + m1 * blo(v1.w) + m2 * blo(v2.w) + m3 * blo(v3.w);
        acc[7] += bhi(v0.w) + m1 * bhi(v1.w) + m2 * bhi(v2.w) + m3 * bhi(v3.w);
    }
    float ri = rsi[node];
    u16 o[8];
#pragma unroll
    for (int i = 0; i < 8; ++i) o[i] = f2b(acc[i] * ri);
    uint4 ov;
    ov.x = o[0] | ((unsigned)o[1] << 16);
    ov.y = o[2] | ((unsigned)o[3] << 16);
    ov.z = o[4] | ((unsigned)o[5] << 16);
    ov.w = o[6] | ((unsigned)o[7] << 16);
    *(uint4*)(out + (size_t)node * KPAD + fc) = ov;
}

// ---------- H-dim aggregation, transposed-bucket reads ----------
__global__ __launch_bounds__(256) void gather_h_kernel(
        const u16* __restrict__ h, const int* __restrict__ bucket,
        const int* __restrict__ cnti, const float* __restrict__ rso,
        const float* __restrict__ rsi, u16* __restrict__ out) {
    int node = blockIdx.x * 8 + (threadIdx.x >> 5);
    int fc = (threadIdx.x & 31) * 8;     // 8 bf16 = 16 B per thread
    int deg = cnti[node]; if (deg > DEGCAP) deg = DEGCAP;
    const int* bk = bucket + node;
    float acc[8] = {};
    for (int base = 0; base < deg; base += 4) {
        int i0 = bk[(size_t)base * NN2];
        int i1 = (base + 1 < deg) ? bk[(size_t)(base + 1) * NN2] : i0;
        int i2 = (base + 2 < deg) ? bk[(size_t)(base + 2) * NN2] : i0;
        int i3 = (base + 3 < deg) ? bk[(size_t)(base + 3) * NN2] : i0;
        float w0 = rso[i0];
        float w1 = (base + 1 < deg) ? rso[i1] : 0.f;
        float w2 = (base + 2 < deg) ? rso[i2] : 0.f;
        float w3 = (base + 3 < deg) ? rso[i3] : 0.f;
        uint4 v0 = *(const uint4*)(h + (size_t)i0 * H + fc);
        uint4 v1 = *(const uint4*)(h + (size_t)i1 * H + fc);
        uint4 v2 = *(const uint4*)(h + (size_t)i2 * H + fc);
        uint4 v3 = *(const uint4*)(h + (size_t)i3 * H + fc);
        acc[0] += blo(v0.x) * w0 + blo(v1.x) * w1 + blo(v2.x) * w2 + blo(v3.x) * w3;
        acc[1] += bhi(v0.x) * w0 + bhi(v1.x) * w1 + bhi(v2.x) * w2 + bhi(v3.x) * w3;
        acc[2] += blo(v0.y) * w0 + blo(v1.y) * w1 + blo(v2.y) * w2 + blo(v3.y) * w3;
        acc[3] += bhi(v0.y) * w0 + bhi(v1.y) * w1 + bhi(v2.y) * w2 + bhi(v3.y) * w3;
        acc[4] += blo(v0.z) * w0 + blo(v1.z) * w1 + blo(v2.z) * w2 + blo(v3.z) * w3;
        acc[5] += bhi(v0.z) * w0 + bhi(v1.z) * w1 + bhi(v2.z) * w2 + bhi(v3.z) * w3;
        acc[6] += blo(v0.w) * w0 + blo(v1.w) * w1 + blo(v2.w) * w2 + blo(v3.w) * w3;
        acc[7] += bhi(v0.w) * w0 + bhi(v1.w) * w1 + bhi(v2.w) * w2 + bhi(v3.w) * w3;
    }
    float ri = rsi[node];
    u16 o[8];
#pragma unroll
    for (int i = 0; i < 8; ++i) o[i] = f2b(acc[i] * ri);
    uint4 ov;
    ov.x = o[0] | ((unsigned)o[1] << 16);
    ov.y = o[2] | ((unsigned)o[3] << 16);
    ov.z = o[4] | ((unsigned)o[5] << 16);
    ov.w = o[6] | ((unsigned)o[7] << 16);
    *(uint4*)(out + (size_t)node * H + fc) = ov;
}

// ---------- weight prep: fp32 row-major -> bf16 transposed ----------
__global__ void prep_w0_kernel(const float* __restrict__ W0, u16* __restrict__ Wt0) {
    int i = blockIdx.x * 256 + threadIdx.x;  // 256*128
    int n = i >> 7, k = i & 127;
    float v = (k < INDIM) ? W0[(size_t)k * H + n] : 0.f;
    Wt0[i] = f2b(v);
}

__global__ void prep_gcr_kernel(const float* __restrict__ W, u16* __restrict__ Wt) {
    int i = blockIdx.x * 256 + threadIdx.x;  // 65536 per layer
    int l = blockIdx.y;                      // 0..9
    int n = i >> 8, k = i & 255;
    Wt[(size_t)l * 65536 + i] = f2b(W[(size_t)l * 65536 + (size_t)k * H + n]);
}

__global__ void prep_w1_kernel(const float* __restrict__ W, u16* __restrict__ Wt) {
    int i = blockIdx.x * 256 + threadIdx.x;  // 1024 * 576
    if (i >= 1024 * ZK) return;
    int n = i / ZK, k = i - n * ZK;
    float v = (k < 520) ? W[(size_t)k * 1024 + n] : 0.f;
    Wt[i] = f2b(v);
}

__global__ void prep_w2_kernel(const float* __restrict__ W, u16* __restrict__ Wt) {
    int i = blockIdx.x * 256 + threadIdx.x;  // 512 * 1024
    int n = i >> 10, k = i & 1023;
    Wt[i] = f2b(W[(size_t)k * 512 + n]);
}

// ---------- bf16 MFMA GEMM helpers ----------
__device__ inline void ldg_lds16(const u16* g, u16* l) {
    __builtin_amdgcn_global_load_lds(
        (const __attribute__((address_space(1))) unsigned int*)g,
        (__attribute__((address_space(3))) unsigned int*)l, 16, 0, 0);
}
__device__ inline float actf(float v, int act) {
    if (act == 1) return fmaxf(v, 0.f);
    if (act == 2) return (v > 0.f) ? v : 0.01f * v;
    return v;
}

// ---------- 128x128 MFMA GEMM, BK=64, XOR-swizzled staging ----------
// LDS slot (row, seg) holds global k-seg (seg ^ (row&7)) -> staging stays
// linear (global_load_lds constraint) while fragment reads are bank-clean.
// grid (N/128, M/128): col fastest -> A-tile re-read L2/LLC-hot.
__global__ __launch_bounds__(256) void gemm_mfma_kernel(
        const u16* __restrict__ A, int lda,
        const u16* __restrict__ Bt, int ldb,
        const float* __restrict__ bias, u16* __restrict__ C, int ldc,
        int Kiters, int act) {   // Kiters = K/64
    __shared__ __align__(16) u16 smem[128 * CPITCH];  // 33 KB; overlays As/Bs
    u16* As = smem;           // 128 x 64 u16 = 16 KB
    u16* Bs = smem + 8192;    // 16 KB
    int t = threadIdx.x;
    int wave = t >> 6, lane = t & 63;
    int wr = wave >> 1, wc = wave & 1;
    int row0 = blockIdx.y * 128, col0 = blockIdx.x * 128;

    // staging: chunk c covers rows c*32..c*32+31; thread t -> row c*32+(t>>3),
    // LDS seg (t&7); source k-seg = (t&7) ^ (row&7)  [XOR swizzle on source]
    int sr = t >> 3;                       // 0..31
    int ksrc = (((t & 7) ^ (sr & 7))) * 8; // swizzled source k-offset (elems)
    const u16* Ag[4];
    const u16* Bg[4];
#pragma unroll
    for (int c = 0; c < 4; ++c) {
        Ag[c] = A + (size_t)(row0 + c * 32 + sr) * lda + ksrc;
        Bg[c] = Bt + (size_t)(col0 + c * 32 + sr) * ldb + ksrc;
    }
    u16* AsW = As + wave * 512;   // wave-uniform LDS base (HW adds lane*16)
    u16* BsW = Bs + wave * 512;

    f32x4 acc[4][4] = {};
    int mrow = lane & 15;
    int q = lane >> 4;            // 0..3

    for (int kt = 0; kt < Kiters; ++kt) {
#pragma unroll
        for (int c = 0; c < 4; ++c) ldg_lds16(Ag[c], AsW + c * 2048);
#pragma unroll
        for (int c = 0; c < 4; ++c) ldg_lds16(Bg[c], BsW + c * 2048);
        __syncthreads();
#pragma unroll
        for (int kk = 0; kk < 2; ++kk) {
            short8 a[4], b[4];
#pragma unroll
            for (int mt = 0; mt < 4; ++mt) {
                int row = wr * 64 + mt * 16 + mrow;
                int seg = (kk * 4 + q) ^ (row & 7);
                a[mt] = *(const short8*)(As + row * 64 + seg * 8);
            }
#pragma unroll
            for (int nt = 0; nt < 4; ++nt) {
                int row = wc * 64 + nt * 16 + mrow;
                int seg = (kk * 4 + q) ^ (row & 7);
                b[nt] = *(const short8*)(Bs + row * 64 + seg * 8);
            }
#pragma unroll
            for (int mt = 0; mt < 4; ++mt)
#pragma unroll
                for (int nt = 0; nt < 4; ++nt)
                    acc[mt][nt] = __builtin_amdgcn_mfma_f32_16x16x32_bf16(
                        a[mt], b[nt], acc[mt][nt], 0, 0, 0);
        }
        __syncthreads();
#pragma unroll
        for (int c = 0; c < 4; ++c) { Ag[c] += 64; Bg[c] += 64; }
    }

    // epilogue: stage C tile in LDS (CPITCH), coalesced dwordx4 stores
#pragma unroll
    for (int mt = 0; mt < 4; ++mt) {
        int rl = wr * 64 + mt * 16 + q * 4;
#pragma unroll
        for (int nt = 0; nt < 4; ++nt) {
            int cl = wc * 64 + nt * 16 + mrow;
            float bv = bias[col0 + cl];
#pragma unroll
            for (int qq = 0; qq < 4; ++qq) {
                float v = actf(acc[mt][nt][qq] + bv, act);
                smem[(size_t)(rl + qq) * CPITCH + cl] = f2b(v);
            }
        }
    }
    __syncthreads();
    int rr = t >> 4;
    int seg = t & 15;
#pragma unroll
    for (int pass = 0; pass < 8; ++pass) {
        int row = pass * 16 + rr;
        uint4 val = *(const uint4*)(smem + (size_t)row * CPITCH + seg * 8);
        *(uint4*)(C + (size_t)(row0 + row) * ldc + col0 + seg * 8) = val;
    }
}

// ---------- pooling (merged): graph g in [0,4096) -> z[g&2047, (g>>11)*256+] ----------
__global__ __launch_bounds__(256) void pool_kernel(const u16* __restrict__ h,
                                                   u16* __restrict__ z) {
    int g = blockIdx.x, f = threadIdx.x;
    float acc = 0.f;
    const u16* base = h + (size_t)g * 40 * H + f;
#pragma unroll
    for (int j = 0; j < 40; ++j) acc += b2f(base[j * H]);
    int zrow = g & (NB - 1);
    int zoff = (g >> 11) * H;
    z[(size_t)zrow * ZK + zoff + f] = f2b(acc);
}

__global__ void copy_add_kernel(const float* __restrict__ add, u16* __restrict__ z) {
    int i = blockIdx.x * 256 + threadIdx.x;
    if (i < NB * 8) {
        int g = i >> 3, a = i & 7;
        z[(size_t)g * ZK + 512 + a] = f2b(add[i]);
    }
}

// ---------- final GEMV: out[r] = sum_k m2b[r,k]*w[k] + b ----------
__global__ void gemv_out_kernel(const u16* __restrict__ A, const float* __restrict__ w,
                                const float* __restrict__ b, float* __restrict__ out, int K) {
    int wave = threadIdx.x >> 6;
    int lane = threadIdx.x & 63;
    int row = blockIdx.x * 4 + wave;
    float acc = 0.f;
    for (int k = lane; k < K; k += 64) acc += b2f(A[(size_t)row * K + k]) * w[k];
#pragma unroll
    for (int off = 32; off > 0; off >>= 1) acc += __shfl_down(acc, off, 64);
    if (lane == 0) out[row] = acc + b[0];
}

extern "C" void kernel_launch(void* const* d_in, const int* in_sizes, int n_in,
                              void* d_out, int out_size, void* d_ws, size_t ws_size,
                              hipStream_t stream) {
    const int*   cat_src = (const int*)d_in[0];
    const int*   cat_dst = (const int*)d_in[1];
    const float* cat_x   = (const float*)d_in[3];
    const int*   an_src  = (const int*)d_in[4];
    const int*   an_dst  = (const int*)d_in[5];
    const float* an_x    = (const float*)d_in[7];
    const float* add_f   = (const float*)d_in[8];
    const float* W0      = (const float*)d_in[9];
    const float* b0      = (const float*)d_in[10];
    const float* gcrW    = (const float*)d_in[11];
    const float* gcrb    = (const float*)d_in[12];
    const float* mW1     = (const float*)d_in[13];
    const float* mb1     = (const float*)d_in[14];
    const float* mW2     = (const float*)d_in[15];
    const float* mb2     = (const float*)d_in[16];
    const float* mW3     = (const float*)d_in[17];
    const float* mb3     = (const float*)d_in[18];
    float* out = (float*)d_out;

    // ---- workspace carve (~205 MB; xbp/aggx alias hA/hB dead ranges) ----
    char* p = (char*)d_ws;
    auto alloc = [&](size_t bytes) -> void* {
        void* rp = (void*)p;
        p += (bytes + 255) & ~(size_t)255;
        return rp;
    };
    int*   dego   = (int*)alloc((size_t)NN2 * 4);
    int*   cnti   = (int*)alloc((size_t)NN2 * 4);
    int*   bucket = (int*)alloc((size_t)NN2 * DEGCAP * 4);
    float* rso    = (float*)alloc((size_t)NN2 * 4);
    float* rsi    = (float*)alloc((size_t)NN2 * 4);
    u16*   hA     = (u16*)alloc((size_t)NN2 * H * 2);   // 84 MB
    u16*   hB     = (u16*)alloc((size_t)NN2 * H * 2);   // 84 MB
    u16*   Wt0    = (u16*)alloc((size_t)H * KPAD * 2);
    u16*   Wtg    = (u16*)alloc((size_t)10 * H * H * 2);
    u16*   Wt1    = (u16*)alloc((size_t)1024 * ZK * 2);
    u16*   Wt2    = (u16*)alloc((size_t)512 * 1024 * 2);
    u16*   zb     = (u16*)alloc((size_t)NB * ZK * 2);
    u16*   m1b    = (u16*)alloc((size_t)NB * 1024 * 2);
    u16*   m2b    = (u16*)alloc((size_t)NB * 512 * 2);
    u16*   xbp    = hA;   // NN2*KPAD*2 = 42 MB, dead after gather_x
    u16*   aggx   = hB;   // NN2*KPAD*2 = 42 MB, dead after first GEMM
    (void)ws_size; (void)in_sizes; (void)n_in; (void)out_size;

    // weight prep (bf16 transposed)
    prep_w0_kernel<<<(H * KPAD) / 256, 256, 0, stream>>>(W0, Wt0);
    prep_gcr_kernel<<<dim3(H * H / 256, 10), 256, 0, stream>>>(gcrW, Wtg);
    prep_w1_kernel<<<(1024 * ZK + 255) / 256, 256, 0, stream>>>(mW1, Wt1);
    prep_w2_kernel<<<(512 * 1024) / 256, 256, 0, stream>>>(mW2, Wt2);
    hipMemsetAsync(zb, 0, (size_t)NB * ZK * 2, stream);  // zero K-pad cols
    hipMemsetAsync(dego, 0, (size_t)NN2 * 4, stream);
    hipMemsetAsync(cnti, 0, (size_t)NN2 * 4, stream);

    // merged graph prep
    fill_kernel<<<NE2 / 256, 256, 0, stream>>>(cat_src, cat_dst, an_src, an_dst,
                                               dego, cnti, bucket);
    rsqrt_kernel<<<NN2 / 256, 256, 0, stream>>>(dego, cnti, rso, rsi);

    // first conv (merged): prescale (padded rows) -> gather -> GEMM K=128
    prescale_x_kernel<<<NN2 / 4, 256, 0, stream>>>(cat_x, an_x, rso, xbp);
    gather_x_kernel<<<NN2 / 16, 256, 0, stream>>>(xbp, bucket, cnti, rsi, aggx);
    gemm_mfma_kernel<<<dim3(H / 128, NN2 / 128), 256, 0, stream>>>(
        aggx, KPAD, Wt0, KPAD, b0, hA, H, KPAD / 64, 0);

    // 10 conv layers (merged): gather hA->hB, GEMM hB->hA
    for (int l = 0; l < 10; ++l) {
        gather_h_kernel<<<NN2 / 8, 256, 0, stream>>>(hA, bucket, cnti, rso, rsi, hB);
        gemm_mfma_kernel<<<dim3(H / 128, NN2 / 128), 256, 0, stream>>>(
            hB, H, Wtg + (size_t)l * H * H, H, gcrb + (size_t)l * H, hA, H,
            H / 64, 1);
    }
    pool_kernel<<<NB2, 256, 0, stream>>>(hA, zb);
    copy_add_kernel<<<(NB * 8 + 255) / 256, 256, 0, stream>>>(add_f, zb);

    // MLP head (bf16 MFMA)
    gemm_mfma_kernel<<<dim3(1024 / 128, NB / 128), 256, 0, stream>>>(
        zb, ZK, Wt1, ZK, mb1, m1b, 1024, ZK / 64, 2);
    gemm_mfma_kernel<<<dim3(512 / 128, NB / 128), 256, 0, stream>>>(
        m1b, 1024, Wt2, 1024, mb2, m2b, 512, 1024 / 64, 2);
    gemv_out_kernel<<<NB / 4, 256, 0, stream>>>(m2b, mW3, mb3, out, 512);
}